// Round 8
// baseline (453.003 us; speedup 1.0000x reference)
//
#include <hip/hip_runtime.h>
#include <hip/hip_bf16.h>

#define N_NODES 4096
#define DMODEL  1024
#define NHEAD   16
#define HDIM    64
#define NOUT    3072   // concat Q|K|V output columns

typedef __attribute__((ext_vector_type(8))) short short8v;
typedef __attribute__((ext_vector_type(4))) float f32x4;
typedef __attribute__((ext_vector_type(16))) float f32x16;
typedef __attribute__((ext_vector_type(4))) unsigned short ushort4v;
typedef __attribute__((ext_vector_type(4))) unsigned int u32x4;

static __device__ __forceinline__ void gload_lds16(const void* g, void* l) {
  __builtin_amdgcn_global_load_lds((const __attribute__((address_space(1))) void*)g,
                                   (__attribute__((address_space(3))) void*)l, 16, 0, 0);
}

static __device__ __forceinline__ unsigned cvtpk(float a, float b) {
  unsigned r;
  asm("v_cvt_pk_bf16_f32 %0, %1, %2" : "=v"(r) : "v"(a), "v"(b));
  return r;
}

// ---------- pass 1a: node_emb fp32 -> bf16 ----------
__global__ void cvt_x_kernel(const float* __restrict__ x, __hip_bfloat16* __restrict__ xb) {
  int i = blockIdx.x * blockDim.x + threadIdx.x;
  float4 v = ((const float4*)x)[i];
  union { ushort4v u; __hip_bfloat16 h[4]; } o;
  o.h[0] = __float2bfloat16(v.x);
  o.h[1] = __float2bfloat16(v.y);
  o.h[2] = __float2bfloat16(v.z);
  o.h[3] = __float2bfloat16(v.w);
  ((ushort4v*)xb)[i] = o.u;
}

// ---------- pass 1b: W[in][out] fp32 -> WT[out][in] bf16 (q|k|v stacked) ----------
__global__ void transpose_w_kernel(const float* __restrict__ Wq, const float* __restrict__ Wk,
                                   const float* __restrict__ Wv, __hip_bfloat16* __restrict__ WT) {
  __shared__ float tile[32][33];
  const float* W = blockIdx.z == 0 ? Wq : (blockIdx.z == 1 ? Wk : Wv);
  int o0 = blockIdx.x * 32, i0 = blockIdx.y * 32;
  int tx = threadIdx.x, ty = threadIdx.y;  // 32 x 8
#pragma unroll
  for (int j = 0; j < 32; j += 8)
    tile[ty + j][tx] = W[(size_t)(i0 + ty + j) * DMODEL + o0 + tx];
  __syncthreads();
  __hip_bfloat16* outp = WT + (size_t)blockIdx.z * DMODEL * DMODEL;
#pragma unroll
  for (int j = 0; j < 32; j += 8)
    outp[(size_t)(o0 + ty + j) * DMODEL + i0 + tx] = __float2bfloat16(tile[tx][ty + j]);
}

// ---------- pass 2: fused QKV GEMM, 128x128x32 ----------
// Q output is pre-scaled by 0.125*log2(e) so attention works in exp2 domain.
__global__ __launch_bounds__(256, 2) void gemm_qkv_kernel(
    const __hip_bfloat16* __restrict__ X, const __hip_bfloat16* __restrict__ WT,
    const float* __restrict__ bq, const float* __restrict__ bk, const float* __restrict__ bv,
    __hip_bfloat16* __restrict__ Qo, __hip_bfloat16* __restrict__ Ko, __hip_bfloat16* __restrict__ Vt) {
  __shared__ __hip_bfloat16 As[128 * 32];
  __shared__ __hip_bfloat16 Bs[128 * 32];
  const int t = threadIdx.x;
  const int lane = t & 63;
  const int w = t >> 6, wr = w >> 1, wc = w & 1;
  const int bm = blockIdx.y, bn = blockIdx.x;

  f32x4 acc[4][4] = {};

  const int rowA = t >> 2;
  const int koff = (t & 3) * 8;
  const __hip_bfloat16* Ag0 = X + (size_t)(bm * 128 + rowA) * DMODEL + koff;
  const __hip_bfloat16* Ag1 = X + (size_t)(bm * 128 + 64 + rowA) * DMODEL + koff;
  const __hip_bfloat16* Bg0 = WT + (size_t)(bn * 128 + rowA) * DMODEL + koff;
  const __hip_bfloat16* Bg1 = WT + (size_t)(bn * 128 + 64 + rowA) * DMODEL + koff;
  __hip_bfloat16* Al0 = &As[t * 8];
  __hip_bfloat16* Al1 = &As[(t + 256) * 8];
  __hip_bfloat16* Bl0 = &Bs[t * 8];
  __hip_bfloat16* Bl1 = &Bs[(t + 256) * 8];

  const short* As_s = (const short*)As;
  const short* Bs_s = (const short*)Bs;
  const int fr = lane & 15, fk = (lane >> 4) * 8;

  for (int kt = 0; kt < DMODEL / 32; ++kt) {
    gload_lds16(Ag0 + kt * 32, Al0);
    gload_lds16(Ag1 + kt * 32, Al1);
    gload_lds16(Bg0 + kt * 32, Bl0);
    gload_lds16(Bg1 + kt * 32, Bl1);
    __syncthreads();
    short8v a[4], b[4];
#pragma unroll
    for (int m = 0; m < 4; ++m)
      a[m] = *(const short8v*)&As_s[(wr * 64 + m * 16 + fr) * 32 + fk];
#pragma unroll
    for (int n = 0; n < 4; ++n)
      b[n] = *(const short8v*)&Bs_s[(wc * 64 + n * 16 + fr) * 32 + fk];
#pragma unroll
    for (int m = 0; m < 4; ++m)
#pragma unroll
      for (int n = 0; n < 4; ++n)
        acc[m][n] = __builtin_amdgcn_mfma_f32_16x16x32_bf16(a[m], b[n], acc[m][n], 0, 0, 0);
    __syncthreads();
  }

  const int row0 = bm * 128 + wr * 64;
  const int col0 = bn * 128 + wc * 64;
  const int which = col0 >> 10;
  const float* bias = which == 0 ? bq : (which == 1 ? bk : bv);
  const float QSCALE = 0.18033688011112042f;  // 0.125 * log2(e)
#pragma unroll
  for (int m = 0; m < 4; ++m) {
#pragma unroll
    for (int n = 0; n < 4; ++n) {
#pragma unroll
      for (int i = 0; i < 4; ++i) {
        int r = row0 + m * 16 + (lane >> 4) * 4 + i;
        int c = col0 + n * 16 + (lane & 15);
        int oo = c & 1023;
        float v = acc[m][n][i] + bias[oo];
        if (which == 0) v *= QSCALE;
        int h = oo >> 6, d = oo & 63;
        __hip_bfloat16 hv = __float2bfloat16(v);
        if (which == 0)      Qo[((size_t)h << 18) + r * 64 + d] = hv;
        else if (which == 1) Ko[((size_t)h << 18) + r * 64 + d] = hv;
        else                 Vt[((size_t)h << 18) + d * 4096 + r] = hv;
      }
    }
  }
}

// ---------- pass 3: flash attention, 64 q-rows per wave, NSPLIT=4 ----------
// Each wave owns q-blocks A (q0..q0+31) and B (q0+32..q0+63); every K/V LDS
// fragment read feeds 2 MFMAs. Grid 1024 = 16 heads x 16 qb x 4 KV-splits
// -> 4 blocks/CU = 4 waves/SIMD for cross-pipe MFMA/VALU overlap.
__global__ __launch_bounds__(256, 4) void attn64_kernel(
    const __hip_bfloat16* __restrict__ Q, const __hip_bfloat16* __restrict__ K,
    const __hip_bfloat16* __restrict__ Vt,
    __hip_bfloat16* __restrict__ Opart, float* __restrict__ lpart) {
  __shared__ __align__(16) short lds_k[2][64 * 64];
  __shared__ __align__(16) short lds_v[2][64 * 64];

  // 1024 blocks; XCD-bijective; 128 consecutive lin per XCD = 2 heads L2-resident
  const int bid = blockIdx.x;
  const int lin = (bid & 7) * 128 + (bid >> 3);
  const int h = lin >> 6, qb = (lin & 63) >> 2, split = lin & 3;

  const int t = threadIdx.x, lane = t & 63, w = t >> 6;
  const int lq = lane & 31, hi = lane >> 5;

  const short* Qh = (const short*)Q + ((size_t)h << 18);
  const short* Kh = (const short*)K + ((size_t)h << 18);
  const short* Vh = (const short*)Vt + ((size_t)h << 18);

  const int q0 = qb * 256 + w * 64;

  // Q B-fragments for both q-blocks: lane holds Q[q][kk*16 + hi*8 .. +8]
  short8v qfA[4], qfB[4];
#pragma unroll
  for (int kk = 0; kk < 4; ++kk) {
    qfA[kk] = *(const short8v*)&Qh[(q0 + lq) * 64 + kk * 16 + hi * 8];
    qfB[kk] = *(const short8v*)&Qh[(q0 + 32 + lq) * 64 + kk * 16 + hi * 8];
  }

  // XOR-swizzled ds_read offsets (elements): row = half*32+lq, chunk = kk*2+hi
  int off8[2][4];
#pragma unroll
  for (int half = 0; half < 2; ++half)
#pragma unroll
    for (int kk = 0; kk < 4; ++kk)
      off8[half][kk] = (half * 32 + lq) * 64 + (((kk * 2 + hi) ^ (lq & 7)) * 8);

  // staging: 512 x 16B chunks per tile; LDS linear dest, pre-swizzled global src
  auto stage = [&](int kt, int b) {
#pragma unroll
    for (int i = 0; i < 2; ++i) {
      int c = w * 128 + i * 64 + lane;
      int row = c >> 3, ss = (c & 7) ^ (row & 7);
      gload_lds16(Kh + (size_t)(kt * 64 + row) * 64 + ss * 8, &lds_k[b][c * 8]);
    }
#pragma unroll
    for (int i = 0; i < 2; ++i) {
      int c = w * 128 + i * 64 + lane;
      int row = c >> 3, ss = (c & 7) ^ (row & 7);
      gload_lds16(Vh + (size_t)row * 4096 + kt * 64 + ss * 8, &lds_v[b][c * 8]);
    }
  };

  f32x16 oA0 = {}, oA1 = {}, oB0 = {}, oB1 = {};
  float lA_r = 0.f, lB_r = 0.f;

  const int NT = 16;
  const int kt0 = split * NT;

  stage(kt0, 0);

  for (int it = 0; it < NT; ++it) {
    const int cur = it & 1;
    __builtin_amdgcn_s_barrier();  // B1: all waves done reading buf cur^1
    if (it + 1 < NT) {
      stage(kt0 + it + 1, cur ^ 1);
      asm volatile("s_waitcnt vmcnt(4)" ::: "memory");  // cur tile landed
    } else {
      asm volatile("s_waitcnt vmcnt(0)" ::: "memory");
    }
    __builtin_amdgcn_s_barrier();  // B2: buf cur staged by all waves
    __builtin_amdgcn_sched_barrier(0);  // pin ds_reads below B2

    const short* kp = lds_k[cur];
    const short* vp = lds_v[cur];

    // S^T = mfma(K, Q): each ka read feeds both q-blocks
    f32x16 sA0 = {}, sA1 = {}, sB0 = {}, sB1 = {};
    __builtin_amdgcn_s_setprio(1);
#pragma unroll
    for (int kk = 0; kk < 4; ++kk) {
      short8v ka0 = *(const short8v*)&kp[off8[0][kk]];
      sA0 = __builtin_amdgcn_mfma_f32_32x32x16_bf16(ka0, qfA[kk], sA0, 0, 0, 0);
      sB0 = __builtin_amdgcn_mfma_f32_32x32x16_bf16(ka0, qfB[kk], sB0, 0, 0, 0);
      short8v ka1 = *(const short8v*)&kp[off8[1][kk]];
      sA1 = __builtin_amdgcn_mfma_f32_32x32x16_bf16(ka1, qfA[kk], sA1, 0, 0, 0);
      sB1 = __builtin_amdgcn_mfma_f32_32x32x16_bf16(ka1, qfB[kk], sB1, 0, 0, 0);
    }
    __builtin_amdgcn_s_setprio(0);

    // p = exp2(s) raw; per-lane partial l; pack to bf16 A-frags (per q-block)
    short8v paA[4], paB[4];
    {
#pragma unroll
      for (int j = 0; j < 16; ++j) { sA0[j] = __builtin_amdgcn_exp2f(sA0[j]); lA_r += sA0[j]; }
#pragma unroll
      for (int j = 0; j < 16; ++j) { sA1[j] = __builtin_amdgcn_exp2f(sA1[j]); lA_r += sA1[j]; }
#pragma unroll
      for (int half = 0; half < 2; ++half) {
        const f32x16& s = half ? sA1 : sA0;
#pragma unroll
        for (int g = 0; g < 2; ++g) {
          unsigned a0 = cvtpk(s[g * 8 + 0], s[g * 8 + 1]), a1 = cvtpk(s[g * 8 + 2], s[g * 8 + 3]);
          unsigned b0 = cvtpk(s[g * 8 + 4], s[g * 8 + 5]), b1 = cvtpk(s[g * 8 + 6], s[g * 8 + 7]);
          asm volatile("v_permlane32_swap_b32 %0, %1" : "+v"(a0), "+v"(b0));
          asm volatile("v_permlane32_swap_b32 %0, %1" : "+v"(a1), "+v"(b1));
          u32x4 u = {a0, a1, b0, b1};
          paA[half * 2 + g] = __builtin_bit_cast(short8v, u);
        }
      }
#pragma unroll
      for (int j = 0; j < 16; ++j) { sB0[j] = __builtin_amdgcn_exp2f(sB0[j]); lB_r += sB0[j]; }
#pragma unroll
      for (int j = 0; j < 16; ++j) { sB1[j] = __builtin_amdgcn_exp2f(sB1[j]); lB_r += sB1[j]; }
#pragma unroll
      for (int half = 0; half < 2; ++half) {
        const f32x16& s = half ? sB1 : sB0;
#pragma unroll
        for (int g = 0; g < 2; ++g) {
          unsigned a0 = cvtpk(s[g * 8 + 0], s[g * 8 + 1]), a1 = cvtpk(s[g * 8 + 2], s[g * 8 + 3]);
          unsigned b0 = cvtpk(s[g * 8 + 4], s[g * 8 + 5]), b1 = cvtpk(s[g * 8 + 6], s[g * 8 + 7]);
          asm volatile("v_permlane32_swap_b32 %0, %1" : "+v"(a0), "+v"(b0));
          asm volatile("v_permlane32_swap_b32 %0, %1" : "+v"(a1), "+v"(b1));
          u32x4 u = {a0, a1, b0, b1};
          paB[half * 2 + g] = __builtin_bit_cast(short8v, u);
        }
      }
    }

    // O += P V: each vb read feeds both q-blocks
    __builtin_amdgcn_s_setprio(1);
#pragma unroll
    for (int kk = 0; kk < 4; ++kk) {
      short8v vb0 = *(const short8v*)&vp[off8[0][kk]];
      oA0 = __builtin_amdgcn_mfma_f32_32x32x16_bf16(paA[kk], vb0, oA0, 0, 0, 0);
      oB0 = __builtin_amdgcn_mfma_f32_32x32x16_bf16(paB[kk], vb0, oB0, 0, 0, 0);
      short8v vb1 = *(const short8v*)&vp[off8[1][kk]];
      oA1 = __builtin_amdgcn_mfma_f32_32x32x16_bf16(paA[kk], vb1, oA1, 0, 0, 0);
      oB1 = __builtin_amdgcn_mfma_f32_32x32x16_bf16(paB[kk], vb1, oB1, 0, 0, 0);
    }
    __builtin_amdgcn_s_setprio(0);
  }

  // epilogue: unnormalized bf16 O partials + fp32 l partials
  {
    float lA = lA_r + __shfl_xor(lA_r, 32);
    float lB = lB_r + __shfl_xor(lB_r, 32);
    if (hi == 0) {
      lpart[((split * NHEAD + h) << 12) + q0 + lq] = lA;
      lpart[((split * NHEAD + h) << 12) + q0 + 32 + lq] = lB;
    }
    __hip_bfloat16* Op = Opart + (size_t)split * N_NODES * DMODEL;
#pragma unroll
    for (int r = 0; r < 16; ++r) {
      int ql = (r & 3) + 8 * (r >> 2) + 4 * hi;
      int qgA = q0 + ql, qgB = q0 + 32 + ql;
      Op[(size_t)qgA * DMODEL + (h << 6) + lq] = __float2bfloat16(oA0[r]);
      Op[(size_t)qgA * DMODEL + (h << 6) + 32 + lq] = __float2bfloat16(oA1[r]);
      Op[(size_t)qgB * DMODEL + (h << 6) + lq] = __float2bfloat16(oB0[r]);
      Op[(size_t)qgB * DMODEL + (h << 6) + 32 + lq] = __float2bfloat16(oB1[r]);
    }
  }
}

// ---------- pass 4: out = (ΣO_s) / (Σl_s), 4 bf16 partials ----------
__global__ void combine_kernel(const __hip_bfloat16* __restrict__ Opart,
                               const float* __restrict__ lpart,
                               float* __restrict__ out) {
  int idx = blockIdx.x * 256 + threadIdx.x;  // one f32x4 (4 outputs)
  int n = idx >> 8;
  int c4 = idx & 255;
  int h = c4 >> 4;
  float l = 0.f;
#pragma unroll
  for (int s = 0; s < 4; ++s) l += lpart[((s * NHEAD + h) << 12) + n];
  float inv = 1.0f / l;
  f32x4 o = {};
#pragma unroll
  for (int s = 0; s < 4; ++s) {
    ushort4v a = ((const ushort4v*)(Opart + (size_t)s * N_NODES * DMODEL))[idx];
#pragma unroll
    for (int j = 0; j < 4; ++j)
      o[j] += __uint_as_float((unsigned)(unsigned short)a[j] << 16);
  }
  ((f32x4*)out)[idx] = o * inv;
}

// ---------- fallback (ws too small): single-pass 32q/wave ----------
__global__ __launch_bounds__(256, 2) void attn_single_kernel(
    const __hip_bfloat16* __restrict__ Q, const __hip_bfloat16* __restrict__ K,
    const __hip_bfloat16* __restrict__ Vt, float* __restrict__ out) {
  __shared__ __align__(16) short lds_k[2][64 * 64];
  __shared__ __align__(16) short lds_v[2][64 * 64];
  __shared__ float smc[4][32];
  const int bid = blockIdx.x;
  const int lin = (bid & 7) * 64 + (bid >> 3);
  const int h = lin >> 5, qb = lin & 31;
  const int t = threadIdx.x, lane = t & 63, w = t >> 6;
  const int lq = lane & 31, hi = lane >> 5;
  const short* Qh = (const short*)Q + ((size_t)h << 18);
  const short* Kh = (const short*)K + ((size_t)h << 18);
  const short* Vh = (const short*)Vt + ((size_t)h << 18);
  const int q0 = qb * 128 + w * 32;
  short8v qf[4];
#pragma unroll
  for (int kk = 0; kk < 4; ++kk)
    qf[kk] = *(const short8v*)&Qh[(q0 + lq) * 64 + kk * 16 + hi * 8];
  int off8[2][4];
#pragma unroll
  for (int half = 0; half < 2; ++half)
#pragma unroll
    for (int kk = 0; kk < 4; ++kk)
      off8[half][kk] = (half * 32 + lq) * 64 + (((kk * 2 + hi) ^ (lq & 7)) * 8);
  auto stage = [&](int kt, int b) {
#pragma unroll
    for (int i = 0; i < 2; ++i) {
      int c = w * 128 + i * 64 + lane;
      int row = c >> 3, ss = (c & 7) ^ (row & 7);
      gload_lds16(Kh + (size_t)(kt * 64 + row) * 64 + ss * 8, &lds_k[b][c * 8]);
    }
#pragma unroll
    for (int i = 0; i < 2; ++i) {
      int c = w * 128 + i * 64 + lane;
      int row = c >> 3, ss = (c & 7) ^ (row & 7);
      gload_lds16(Vh + (size_t)row * 4096 + kt * 64 + ss * 8, &lds_v[b][c * 8]);
    }
  };
  f32x16 o0 = {}, o1 = {};
  float l_r = 0.f;
  stage(0, 0);
  for (int kt = 0; kt < 64; ++kt) {
    const int cur = kt & 1;
    __builtin_amdgcn_s_barrier();
    if (kt + 1 < 64) {
      stage(kt + 1, cur ^ 1);
      asm volatile("s_waitcnt vmcnt(4)" ::: "memory");
    } else {
      asm volatile("s_waitcnt vmcnt(0)" ::: "memory");
    }
    __builtin_amdgcn_s_barrier();
    __builtin_amdgcn_sched_barrier(0);
    const short* kp = lds_k[cur];
    const short* vp = lds_v[cur];
    f32x16 s0 = {}, s1 = {};
#pragma unroll
    for (int kk = 0; kk < 4; ++kk) {
      short8v ka0 = *(const short8v*)&kp[off8[0][kk]];
      s0 = __builtin_amdgcn_mfma_f32_32x32x16_bf16(ka0, qf[kk], s0, 0, 0, 0);
      short8v ka1 = *(const short8v*)&kp[off8[1][kk]];
      s1 = __builtin_amdgcn_mfma_f32_32x32x16_bf16(ka1, qf[kk], s1, 0, 0, 0);
    }
#pragma unroll
    for (int j = 0; j < 16; ++j) { s0[j] = __builtin_amdgcn_exp2f(s0[j]); l_r += s0[j]; }
#pragma unroll
    for (int j = 0; j < 16; ++j) { s1[j] = __builtin_amdgcn_exp2f(s1[j]); l_r += s1[j]; }
    short8v pa[4];
#pragma unroll
    for (int half = 0; half < 2; ++half) {
      const f32x16& s = half ? s1 : s0;
#pragma unroll
      for (int g = 0; g < 2; ++g) {
        unsigned a0 = cvtpk(s[g * 8 + 0], s[g * 8 + 1]), a1 = cvtpk(s[g * 8 + 2], s[g * 8 + 3]);
        unsigned b0 = cvtpk(s[g * 8 + 4], s[g * 8 + 5]), b1 = cvtpk(s[g * 8 + 6], s[g * 8 + 7]);
        asm volatile("v_permlane32_swap_b32 %0, %1" : "+v"(a0), "+v"(b0));
        asm volatile("v_permlane32_swap_b32 %0, %1" : "+v"(a1), "+v"(b1));
        u32x4 u = {a0, a1, b0, b1};
        pa[half * 2 + g] = __builtin_bit_cast(short8v, u);
      }
    }
#pragma unroll
    for (int kk = 0; kk < 4; ++kk) {
      short8v vb0 = *(const short8v*)&vp[off8[0][kk]];
      o0 = __builtin_amdgcn_mfma_f32_32x32x16_bf16(pa[kk], vb0, o0, 0, 0, 0);
      short8v vb1 = *(const short8v*)&vp[off8[1][kk]];
      o1 = __builtin_amdgcn_mfma_f32_32x32x16_bf16(pa[kk], vb1, o1, 0, 0, 0);
    }
  }
  {
    float lt = l_r + __shfl_xor(l_r, 32);
    float inv = 1.0f / lt;
    if (lane < 32) smc[w][lq] = inv;
#pragma unroll
    for (int r = 0; r < 16; ++r) {
      int ql = (r & 3) + 8 * (r >> 2) + 4 * hi;
      float iv = smc[w][ql];
      int qg = q0 + ql;
      out[(size_t)qg * DMODEL + (h << 6) + lq] = o0[r] * iv;
      out[(size_t)qg * DMODEL + (h << 6) + 32 + lq] = o1[r] * iv;
    }
  }
}

extern "C" void kernel_launch(void* const* d_in, const int* in_sizes, int n_in,
                              void* d_out, int out_size, void* d_ws, size_t ws_size,
                              hipStream_t stream) {
  const float* node_emb = (const float*)d_in[0];
  const float* Wq = (const float*)d_in[1];
  const float* bq = (const float*)d_in[2];
  const float* Wk = (const float*)d_in[3];
  const float* bk = (const float*)d_in[4];
  const float* Wv = (const float*)d_in[5];
  const float* bv = (const float*)d_in[6];
  float* out = (float*)d_out;

  // ws layout: [Qb|Kb|Vtb live through attn][Xbf|WT dead after GEMM -> Opart/lpart overlay]
  const size_t HSZ = (size_t)NHEAD * N_NODES * HDIM;  // per-matrix elems (4.19M)
  __hip_bfloat16* Qb  = (__hip_bfloat16*)d_ws;
  __hip_bfloat16* Kb  = Qb + HSZ;
  __hip_bfloat16* Vtb = Kb + HSZ;
  __hip_bfloat16* Xbf = Vtb + HSZ;
  __hip_bfloat16* WT  = Xbf + (size_t)N_NODES * DMODEL;

  __hip_bfloat16* Opart = Xbf;  // overlays Xbf/WT (dead after GEMM)
  float* lpart = (float*)(Opart + 4 * (size_t)N_NODES * DMODEL);

  const size_t split_bytes =
      (3 * HSZ + 4 * (size_t)N_NODES * DMODEL) * sizeof(__hip_bfloat16) +
      4 * (size_t)NHEAD * N_NODES * sizeof(float);
  const size_t base_bytes =
      (3 * HSZ + (size_t)N_NODES * DMODEL + (size_t)NOUT * DMODEL) * sizeof(__hip_bfloat16);
  const bool can_split = ws_size >= (split_bytes > base_bytes ? split_bytes : base_bytes);

  cvt_x_kernel<<<(N_NODES * DMODEL) / (256 * 4), 256, 0, stream>>>(node_emb, Xbf);
  transpose_w_kernel<<<dim3(32, 32, 3), dim3(32, 8), 0, stream>>>(Wq, Wk, Wv, WT);
  gemm_qkv_kernel<<<dim3(NOUT / 128, N_NODES / 128), 256, 0, stream>>>(
      Xbf, WT, bq, bk, bv, Qb, Kb, Vtb);

  if (can_split) {
    attn64_kernel<<<1024, 256, 0, stream>>>(Qb, Kb, Vtb, Opart, lpart);
    combine_kernel<<<(N_NODES * DMODEL) / (256 * 4), 256, 0, stream>>>(Opart, lpart, out);
  } else {
    attn_single_kernel<<<512, 256, 0, stream>>>(Qb, Kb, Vtb, out);
  }
}

// Round 9
// 140.587 us; speedup vs baseline: 3.2222x; 3.2222x over previous
//
#include <hip/hip_runtime.h>
#include <hip/hip_bf16.h>

#define N_NODES 4096
#define DMODEL  1024
#define NHEAD   16
#define HDIM    64
#define NOUT    3072   // concat Q|K|V output columns

typedef __attribute__((ext_vector_type(8))) short short8v;
typedef __attribute__((ext_vector_type(4))) float f32x4;
typedef __attribute__((ext_vector_type(16))) float f32x16;
typedef __attribute__((ext_vector_type(4))) unsigned short ushort4v;
typedef __attribute__((ext_vector_type(4))) unsigned int u32x4;

static __device__ __forceinline__ void gload_lds16(const void* g, void* l) {
  __builtin_amdgcn_global_load_lds((const __attribute__((address_space(1))) void*)g,
                                   (__attribute__((address_space(3))) void*)l, 16, 0, 0);
}

static __device__ __forceinline__ unsigned cvtpk(float a, float b) {
  unsigned r;
  asm("v_cvt_pk_bf16_f32 %0, %1, %2" : "=v"(r) : "v"(a), "v"(b));
  return r;
}

// ---------- pass 1a: node_emb fp32 -> bf16 ----------
__global__ void cvt_x_kernel(const float* __restrict__ x, __hip_bfloat16* __restrict__ xb) {
  int i = blockIdx.x * blockDim.x + threadIdx.x;
  float4 v = ((const float4*)x)[i];
  union { ushort4v u; __hip_bfloat16 h[4]; } o;
  o.h[0] = __float2bfloat16(v.x);
  o.h[1] = __float2bfloat16(v.y);
  o.h[2] = __float2bfloat16(v.z);
  o.h[3] = __float2bfloat16(v.w);
  ((ushort4v*)xb)[i] = o.u;
}

// ---------- pass 1b: W[in][out] fp32 -> WT[out][in] bf16 (q|k|v stacked) ----------
__global__ void transpose_w_kernel(const float* __restrict__ Wq, const float* __restrict__ Wk,
                                   const float* __restrict__ Wv, __hip_bfloat16* __restrict__ WT) {
  __shared__ float tile[32][33];
  const float* W = blockIdx.z == 0 ? Wq : (blockIdx.z == 1 ? Wk : Wv);
  int o0 = blockIdx.x * 32, i0 = blockIdx.y * 32;
  int tx = threadIdx.x, ty = threadIdx.y;  // 32 x 8
#pragma unroll
  for (int j = 0; j < 32; j += 8)
    tile[ty + j][tx] = W[(size_t)(i0 + ty + j) * DMODEL + o0 + tx];
  __syncthreads();
  __hip_bfloat16* outp = WT + (size_t)blockIdx.z * DMODEL * DMODEL;
#pragma unroll
  for (int j = 0; j < 32; j += 8)
    outp[(size_t)(o0 + ty + j) * DMODEL + i0 + tx] = __float2bfloat16(tile[tx][ty + j]);
}

// ---------- pass 2: fused QKV GEMM, 128x128x32 ----------
// Q output is pre-scaled by 0.125*log2(e) so attention works in exp2 domain.
__global__ __launch_bounds__(256, 2) void gemm_qkv_kernel(
    const __hip_bfloat16* __restrict__ X, const __hip_bfloat16* __restrict__ WT,
    const float* __restrict__ bq, const float* __restrict__ bk, const float* __restrict__ bv,
    __hip_bfloat16* __restrict__ Qo, __hip_bfloat16* __restrict__ Ko, __hip_bfloat16* __restrict__ Vt) {
  __shared__ __hip_bfloat16 As[128 * 32];
  __shared__ __hip_bfloat16 Bs[128 * 32];
  const int t = threadIdx.x;
  const int lane = t & 63;
  const int w = t >> 6, wr = w >> 1, wc = w & 1;
  const int bm = blockIdx.y, bn = blockIdx.x;

  f32x4 acc[4][4] = {};

  const int rowA = t >> 2;
  const int koff = (t & 3) * 8;
  const __hip_bfloat16* Ag0 = X + (size_t)(bm * 128 + rowA) * DMODEL + koff;
  const __hip_bfloat16* Ag1 = X + (size_t)(bm * 128 + 64 + rowA) * DMODEL + koff;
  const __hip_bfloat16* Bg0 = WT + (size_t)(bn * 128 + rowA) * DMODEL + koff;
  const __hip_bfloat16* Bg1 = WT + (size_t)(bn * 128 + 64 + rowA) * DMODEL + koff;
  __hip_bfloat16* Al0 = &As[t * 8];
  __hip_bfloat16* Al1 = &As[(t + 256) * 8];
  __hip_bfloat16* Bl0 = &Bs[t * 8];
  __hip_bfloat16* Bl1 = &Bs[(t + 256) * 8];

  const short* As_s = (const short*)As;
  const short* Bs_s = (const short*)Bs;
  const int fr = lane & 15, fk = (lane >> 4) * 8;

  for (int kt = 0; kt < DMODEL / 32; ++kt) {
    gload_lds16(Ag0 + kt * 32, Al0);
    gload_lds16(Ag1 + kt * 32, Al1);
    gload_lds16(Bg0 + kt * 32, Bl0);
    gload_lds16(Bg1 + kt * 32, Bl1);
    __syncthreads();
    short8v a[4], b[4];
#pragma unroll
    for (int m = 0; m < 4; ++m)
      a[m] = *(const short8v*)&As_s[(wr * 64 + m * 16 + fr) * 32 + fk];
#pragma unroll
    for (int n = 0; n < 4; ++n)
      b[n] = *(const short8v*)&Bs_s[(wc * 64 + n * 16 + fr) * 32 + fk];
#pragma unroll
    for (int m = 0; m < 4; ++m)
#pragma unroll
      for (int n = 0; n < 4; ++n)
        acc[m][n] = __builtin_amdgcn_mfma_f32_16x16x32_bf16(a[m], b[n], acc[m][n], 0, 0, 0);
    __syncthreads();
  }

  const int row0 = bm * 128 + wr * 64;
  const int col0 = bn * 128 + wc * 64;
  const int which = col0 >> 10;
  const float* bias = which == 0 ? bq : (which == 1 ? bk : bv);
  const float QSCALE = 0.18033688011112042f;  // 0.125 * log2(e)
#pragma unroll
  for (int m = 0; m < 4; ++m) {
#pragma unroll
    for (int n = 0; n < 4; ++n) {
#pragma unroll
      for (int i = 0; i < 4; ++i) {
        int r = row0 + m * 16 + (lane >> 4) * 4 + i;
        int c = col0 + n * 16 + (lane & 15);
        int oo = c & 1023;
        float v = acc[m][n][i] + bias[oo];
        if (which == 0) v *= QSCALE;
        int h = oo >> 6, d = oo & 63;
        __hip_bfloat16 hv = __float2bfloat16(v);
        if (which == 0)      Qo[((size_t)h << 18) + r * 64 + d] = hv;
        else if (which == 1) Ko[((size_t)h << 18) + r * 64 + d] = hv;
        else                 Vt[((size_t)h << 18) + d * 4096 + r] = hv;
      }
    }
  }
}

// ---------- pass 3: flash attention, 64 q-rows per wave, NSPLIT=4 ----------
// Each wave owns q-blocks A (q0..q0+31) and B (q0+32..q0+63); every K/V LDS
// fragment read feeds 2 MFMAs. Grid 1024 = 16 heads x 16 qb x 4 KV-splits.
// launch_bounds kept at (256,2): kernel compiles to ~112 VGPR there, which the
// HW can schedule at 4 blocks/CU anyway (4x112=448 <= 512/SIMD). Forcing
// (256,4) made the allocator squeeze to 64 VGPR -> catastrophic spill (R8).
__global__ __launch_bounds__(256, 2) void attn64_kernel(
    const __hip_bfloat16* __restrict__ Q, const __hip_bfloat16* __restrict__ K,
    const __hip_bfloat16* __restrict__ Vt,
    __hip_bfloat16* __restrict__ Opart, float* __restrict__ lpart) {
  __shared__ __align__(16) short lds_k[2][64 * 64];
  __shared__ __align__(16) short lds_v[2][64 * 64];

  // 1024 blocks; XCD-bijective; 128 consecutive lin per XCD = 2 heads L2-resident
  const int bid = blockIdx.x;
  const int lin = (bid & 7) * 128 + (bid >> 3);
  const int h = lin >> 6, qb = (lin & 63) >> 2, split = lin & 3;

  const int t = threadIdx.x, lane = t & 63, w = t >> 6;
  const int lq = lane & 31, hi = lane >> 5;

  const short* Qh = (const short*)Q + ((size_t)h << 18);
  const short* Kh = (const short*)K + ((size_t)h << 18);
  const short* Vh = (const short*)Vt + ((size_t)h << 18);

  const int q0 = qb * 256 + w * 64;

  // Q B-fragments for both q-blocks: lane holds Q[q][kk*16 + hi*8 .. +8]
  short8v qfA[4], qfB[4];
#pragma unroll
  for (int kk = 0; kk < 4; ++kk) {
    qfA[kk] = *(const short8v*)&Qh[(q0 + lq) * 64 + kk * 16 + hi * 8];
    qfB[kk] = *(const short8v*)&Qh[(q0 + 32 + lq) * 64 + kk * 16 + hi * 8];
  }

  // XOR-swizzled ds_read offsets (elements): row = half*32+lq, chunk = kk*2+hi
  int off8[2][4];
#pragma unroll
  for (int half = 0; half < 2; ++half)
#pragma unroll
    for (int kk = 0; kk < 4; ++kk)
      off8[half][kk] = (half * 32 + lq) * 64 + (((kk * 2 + hi) ^ (lq & 7)) * 8);

  // staging: 512 x 16B chunks per tile; LDS linear dest, pre-swizzled global src
  auto stage = [&](int kt, int b) {
#pragma unroll
    for (int i = 0; i < 2; ++i) {
      int c = w * 128 + i * 64 + lane;
      int row = c >> 3, ss = (c & 7) ^ (row & 7);
      gload_lds16(Kh + (size_t)(kt * 64 + row) * 64 + ss * 8, &lds_k[b][c * 8]);
    }
#pragma unroll
    for (int i = 0; i < 2; ++i) {
      int c = w * 128 + i * 64 + lane;
      int row = c >> 3, ss = (c & 7) ^ (row & 7);
      gload_lds16(Vh + (size_t)row * 4096 + kt * 64 + ss * 8, &lds_v[b][c * 8]);
    }
  };

  f32x16 oA0 = {}, oA1 = {}, oB0 = {}, oB1 = {};
  float lA_r = 0.f, lB_r = 0.f;

  const int NT = 16;
  const int kt0 = split * NT;

  stage(kt0, 0);

  for (int it = 0; it < NT; ++it) {
    const int cur = it & 1;
    __builtin_amdgcn_s_barrier();  // B1: all waves done reading buf cur^1
    if (it + 1 < NT) {
      stage(kt0 + it + 1, cur ^ 1);
      asm volatile("s_waitcnt vmcnt(4)" ::: "memory");  // cur tile landed
    } else {
      asm volatile("s_waitcnt vmcnt(0)" ::: "memory");
    }
    __builtin_amdgcn_s_barrier();  // B2: buf cur staged by all waves
    __builtin_amdgcn_sched_barrier(0);  // pin ds_reads below B2

    const short* kp = lds_k[cur];
    const short* vp = lds_v[cur];

    // S^T = mfma(K, Q): each ka read feeds both q-blocks
    f32x16 sA0 = {}, sA1 = {}, sB0 = {}, sB1 = {};
    __builtin_amdgcn_s_setprio(1);
#pragma unroll
    for (int kk = 0; kk < 4; ++kk) {
      short8v ka0 = *(const short8v*)&kp[off8[0][kk]];
      sA0 = __builtin_amdgcn_mfma_f32_32x32x16_bf16(ka0, qfA[kk], sA0, 0, 0, 0);
      sB0 = __builtin_amdgcn_mfma_f32_32x32x16_bf16(ka0, qfB[kk], sB0, 0, 0, 0);
      short8v ka1 = *(const short8v*)&kp[off8[1][kk]];
      sA1 = __builtin_amdgcn_mfma_f32_32x32x16_bf16(ka1, qfA[kk], sA1, 0, 0, 0);
      sB1 = __builtin_amdgcn_mfma_f32_32x32x16_bf16(ka1, qfB[kk], sB1, 0, 0, 0);
    }
    __builtin_amdgcn_s_setprio(0);

    // p = exp2(s) raw; per-lane partial l; pack to bf16 A-frags (per q-block)
    short8v paA[4], paB[4];
    {
#pragma unroll
      for (int j = 0; j < 16; ++j) { sA0[j] = __builtin_amdgcn_exp2f(sA0[j]); lA_r += sA0[j]; }
#pragma unroll
      for (int j = 0; j < 16; ++j) { sA1[j] = __builtin_amdgcn_exp2f(sA1[j]); lA_r += sA1[j]; }
#pragma unroll
      for (int half = 0; half < 2; ++half) {
        const f32x16& s = half ? sA1 : sA0;
#pragma unroll
        for (int g = 0; g < 2; ++g) {
          unsigned a0 = cvtpk(s[g * 8 + 0], s[g * 8 + 1]), a1 = cvtpk(s[g * 8 + 2], s[g * 8 + 3]);
          unsigned b0 = cvtpk(s[g * 8 + 4], s[g * 8 + 5]), b1 = cvtpk(s[g * 8 + 6], s[g * 8 + 7]);
          asm volatile("v_permlane32_swap_b32 %0, %1" : "+v"(a0), "+v"(b0));
          asm volatile("v_permlane32_swap_b32 %0, %1" : "+v"(a1), "+v"(b1));
          u32x4 u = {a0, a1, b0, b1};
          paA[half * 2 + g] = __builtin_bit_cast(short8v, u);
        }
      }
#pragma unroll
      for (int j = 0; j < 16; ++j) { sB0[j] = __builtin_amdgcn_exp2f(sB0[j]); lB_r += sB0[j]; }
#pragma unroll
      for (int j = 0; j < 16; ++j) { sB1[j] = __builtin_amdgcn_exp2f(sB1[j]); lB_r += sB1[j]; }
#pragma unroll
      for (int half = 0; half < 2; ++half) {
        const f32x16& s = half ? sB1 : sB0;
#pragma unroll
        for (int g = 0; g < 2; ++g) {
          unsigned a0 = cvtpk(s[g * 8 + 0], s[g * 8 + 1]), a1 = cvtpk(s[g * 8 + 2], s[g * 8 + 3]);
          unsigned b0 = cvtpk(s[g * 8 + 4], s[g * 8 + 5]), b1 = cvtpk(s[g * 8 + 6], s[g * 8 + 7]);
          asm volatile("v_permlane32_swap_b32 %0, %1" : "+v"(a0), "+v"(b0));
          asm volatile("v_permlane32_swap_b32 %0, %1" : "+v"(a1), "+v"(b1));
          u32x4 u = {a0, a1, b0, b1};
          paB[half * 2 + g] = __builtin_bit_cast(short8v, u);
        }
      }
    }

    // O += P V: each vb read feeds both q-blocks
    __builtin_amdgcn_s_setprio(1);
#pragma unroll
    for (int kk = 0; kk < 4; ++kk) {
      short8v vb0 = *(const short8v*)&vp[off8[0][kk]];
      oA0 = __builtin_amdgcn_mfma_f32_32x32x16_bf16(paA[kk], vb0, oA0, 0, 0, 0);
      oB0 = __builtin_amdgcn_mfma_f32_32x32x16_bf16(paB[kk], vb0, oB0, 0, 0, 0);
      short8v vb1 = *(const short8v*)&vp[off8[1][kk]];
      oA1 = __builtin_amdgcn_mfma_f32_32x32x16_bf16(paA[kk], vb1, oA1, 0, 0, 0);
      oB1 = __builtin_amdgcn_mfma_f32_32x32x16_bf16(paB[kk], vb1, oB1, 0, 0, 0);
    }
    __builtin_amdgcn_s_setprio(0);
  }

  // epilogue: unnormalized bf16 O partials + fp32 l partials
  {
    float lA = lA_r + __shfl_xor(lA_r, 32);
    float lB = lB_r + __shfl_xor(lB_r, 32);
    if (hi == 0) {
      lpart[((split * NHEAD + h) << 12) + q0 + lq] = lA;
      lpart[((split * NHEAD + h) << 12) + q0 + 32 + lq] = lB;
    }
    __hip_bfloat16* Op = Opart + (size_t)split * N_NODES * DMODEL;
#pragma unroll
    for (int r = 0; r < 16; ++r) {
      int ql = (r & 3) + 8 * (r >> 2) + 4 * hi;
      int qgA = q0 + ql, qgB = q0 + 32 + ql;
      Op[(size_t)qgA * DMODEL + (h << 6) + lq] = __float2bfloat16(oA0[r]);
      Op[(size_t)qgA * DMODEL + (h << 6) + 32 + lq] = __float2bfloat16(oA1[r]);
      Op[(size_t)qgB * DMODEL + (h << 6) + lq] = __float2bfloat16(oB0[r]);
      Op[(size_t)qgB * DMODEL + (h << 6) + 32 + lq] = __float2bfloat16(oB1[r]);
    }
  }
}

// ---------- pass 4: out = (ΣO_s) / (Σl_s), 4 bf16 partials ----------
__global__ void combine_kernel(const __hip_bfloat16* __restrict__ Opart,
                               const float* __restrict__ lpart,
                               float* __restrict__ out) {
  int idx = blockIdx.x * 256 + threadIdx.x;  // one f32x4 (4 outputs)
  int n = idx >> 8;
  int c4 = idx & 255;
  int h = c4 >> 4;
  float l = 0.f;
#pragma unroll
  for (int s = 0; s < 4; ++s) l += lpart[((s * NHEAD + h) << 12) + n];
  float inv = 1.0f / l;
  f32x4 o = {};
#pragma unroll
  for (int s = 0; s < 4; ++s) {
    ushort4v a = ((const ushort4v*)(Opart + (size_t)s * N_NODES * DMODEL))[idx];
#pragma unroll
    for (int j = 0; j < 4; ++j)
      o[j] += __uint_as_float((unsigned)(unsigned short)a[j] << 16);
  }
  ((f32x4*)out)[idx] = o * inv;
}

// ---------- fallback (ws too small): single-pass 32q/wave ----------
__global__ __launch_bounds__(256, 2) void attn_single_kernel(
    const __hip_bfloat16* __restrict__ Q, const __hip_bfloat16* __restrict__ K,
    const __hip_bfloat16* __restrict__ Vt, float* __restrict__ out) {
  __shared__ __align__(16) short lds_k[2][64 * 64];
  __shared__ __align__(16) short lds_v[2][64 * 64];
  __shared__ float smc[4][32];
  const int bid = blockIdx.x;
  const int lin = (bid & 7) * 64 + (bid >> 3);
  const int h = lin >> 5, qb = lin & 31;
  const int t = threadIdx.x, lane = t & 63, w = t >> 6;
  const int lq = lane & 31, hi = lane >> 5;
  const short* Qh = (const short*)Q + ((size_t)h << 18);
  const short* Kh = (const short*)K + ((size_t)h << 18);
  const short* Vh = (const short*)Vt + ((size_t)h << 18);
  const int q0 = qb * 128 + w * 32;
  short8v qf[4];
#pragma unroll
  for (int kk = 0; kk < 4; ++kk)
    qf[kk] = *(const short8v*)&Qh[(q0 + lq) * 64 + kk * 16 + hi * 8];
  int off8[2][4];
#pragma unroll
  for (int half = 0; half < 2; ++half)
#pragma unroll
    for (int kk = 0; kk < 4; ++kk)
      off8[half][kk] = (half * 32 + lq) * 64 + (((kk * 2 + hi) ^ (lq & 7)) * 8);
  auto stage = [&](int kt, int b) {
#pragma unroll
    for (int i = 0; i < 2; ++i) {
      int c = w * 128 + i * 64 + lane;
      int row = c >> 3, ss = (c & 7) ^ (row & 7);
      gload_lds16(Kh + (size_t)(kt * 64 + row) * 64 + ss * 8, &lds_k[b][c * 8]);
    }
#pragma unroll
    for (int i = 0; i < 2; ++i) {
      int c = w * 128 + i * 64 + lane;
      int row = c >> 3, ss = (c & 7) ^ (row & 7);
      gload_lds16(Vh + (size_t)row * 4096 + kt * 64 + ss * 8, &lds_v[b][c * 8]);
    }
  };
  f32x16 o0 = {}, o1 = {};
  float l_r = 0.f;
  stage(0, 0);
  for (int kt = 0; kt < 64; ++kt) {
    const int cur = kt & 1;
    __builtin_amdgcn_s_barrier();
    if (kt + 1 < 64) {
      stage(kt + 1, cur ^ 1);
      asm volatile("s_waitcnt vmcnt(4)" ::: "memory");
    } else {
      asm volatile("s_waitcnt vmcnt(0)" ::: "memory");
    }
    __builtin_amdgcn_s_barrier();
    __builtin_amdgcn_sched_barrier(0);
    const short* kp = lds_k[cur];
    const short* vp = lds_v[cur];
    f32x16 s0 = {}, s1 = {};
#pragma unroll
    for (int kk = 0; kk < 4; ++kk) {
      short8v ka0 = *(const short8v*)&kp[off8[0][kk]];
      s0 = __builtin_amdgcn_mfma_f32_32x32x16_bf16(ka0, qf[kk], s0, 0, 0, 0);
      short8v ka1 = *(const short8v*)&kp[off8[1][kk]];
      s1 = __builtin_amdgcn_mfma_f32_32x32x16_bf16(ka1, qf[kk], s1, 0, 0, 0);
    }
#pragma unroll
    for (int j = 0; j < 16; ++j) { s0[j] = __builtin_amdgcn_exp2f(s0[j]); l_r += s0[j]; }
#pragma unroll
    for (int j = 0; j < 16; ++j) { s1[j] = __builtin_amdgcn_exp2f(s1[j]); l_r += s1[j]; }
    short8v pa[4];
#pragma unroll
    for (int half = 0; half < 2; ++half) {
      const f32x16& s = half ? s1 : s0;
#pragma unroll
      for (int g = 0; g < 2; ++g) {
        unsigned a0 = cvtpk(s[g * 8 + 0], s[g * 8 + 1]), a1 = cvtpk(s[g * 8 + 2], s[g * 8 + 3]);
        unsigned b0 = cvtpk(s[g * 8 + 4], s[g * 8 + 5]), b1 = cvtpk(s[g * 8 + 6], s[g * 8 + 7]);
        asm volatile("v_permlane32_swap_b32 %0, %1" : "+v"(a0), "+v"(b0));
        asm volatile("v_permlane32_swap_b32 %0, %1" : "+v"(a1), "+v"(b1));
        u32x4 u = {a0, a1, b0, b1};
        pa[half * 2 + g] = __builtin_bit_cast(short8v, u);
      }
    }
#pragma unroll
    for (int kk = 0; kk < 4; ++kk) {
      short8v vb0 = *(const short8v*)&vp[off8[0][kk]];
      o0 = __builtin_amdgcn_mfma_f32_32x32x16_bf16(pa[kk], vb0, o0, 0, 0, 0);
      short8v vb1 = *(const short8v*)&vp[off8[1][kk]];
      o1 = __builtin_amdgcn_mfma_f32_32x32x16_bf16(pa[kk], vb1, o1, 0, 0, 0);
    }
  }
  {
    float lt = l_r + __shfl_xor(l_r, 32);
    float inv = 1.0f / lt;
    if (lane < 32) smc[w][lq] = inv;
#pragma unroll
    for (int r = 0; r < 16; ++r) {
      int ql = (r & 3) + 8 * (r >> 2) + 4 * hi;
      float iv = smc[w][ql];
      int qg = q0 + ql;
      out[(size_t)qg * DMODEL + (h << 6) + lq] = o0[r] * iv;
      out[(size_t)qg * DMODEL + (h << 6) + 32 + lq] = o1[r] * iv;
    }
  }
}

extern "C" void kernel_launch(void* const* d_in, const int* in_sizes, int n_in,
                              void* d_out, int out_size, void* d_ws, size_t ws_size,
                              hipStream_t stream) {
  const float* node_emb = (const float*)d_in[0];
  const float* Wq = (const float*)d_in[1];
  const float* bq = (const float*)d_in[2];
  const float* Wk = (const float*)d_in[3];
  const float* bk = (const float*)d_in[4];
  const float* Wv = (const float*)d_in[5];
  const float* bv = (const float*)d_in[6];
  float* out = (float*)d_out;

  // ws layout: [Qb|Kb|Vtb live through attn][Xbf|WT dead after GEMM -> Opart/lpart overlay]
  const size_t HSZ = (size_t)NHEAD * N_NODES * HDIM;  // per-matrix elems (4.19M)
  __hip_bfloat16* Qb  = (__hip_bfloat16*)d_ws;
  __hip_bfloat16* Kb  = Qb + HSZ;
  __hip_bfloat16* Vtb = Kb + HSZ;
  __hip_bfloat16* Xbf = Vtb + HSZ;
  __hip_bfloat16* WT  = Xbf + (size_t)N_NODES * DMODEL;

  __hip_bfloat16* Opart = Xbf;  // overlays Xbf/WT (dead after GEMM)
  float* lpart = (float*)(Opart + 4 * (size_t)N_NODES * DMODEL);

  const size_t split_bytes =
      (3 * HSZ + 4 * (size_t)N_NODES * DMODEL) * sizeof(__hip_bfloat16) +
      4 * (size_t)NHEAD * N_NODES * sizeof(float);
  const size_t base_bytes =
      (3 * HSZ + (size_t)N_NODES * DMODEL + (size_t)NOUT * DMODEL) * sizeof(__hip_bfloat16);
  const bool can_split = ws_size >= (split_bytes > base_bytes ? split_bytes : base_bytes);

  cvt_x_kernel<<<(N_NODES * DMODEL) / (256 * 4), 256, 0, stream>>>(node_emb, Xbf);
  transpose_w_kernel<<<dim3(32, 32, 3), dim3(32, 8), 0, stream>>>(Wq, Wk, Wv, WT);
  gemm_qkv_kernel<<<dim3(NOUT / 128, N_NODES / 128), 256, 0, stream>>>(
      Xbf, WT, bq, bk, bv, Qb, Kb, Vtb);

  if (can_split) {
    attn64_kernel<<<1024, 256, 0, stream>>>(Qb, Kb, Vtb, Opart, lpart);
    combine_kernel<<<(N_NODES * DMODEL) / (256 * 4), 256, 0, stream>>>(Opart, lpart, out);
  } else {
    attn_single_kernel<<<512, 256, 0, stream>>>(Qb, Kb, Vtb, out);
  }
}

// Round 10
// 134.500 us; speedup vs baseline: 3.3681x; 1.0453x over previous
//
#include <hip/hip_runtime.h>
#include <hip/hip_bf16.h>

#define N_NODES 4096
#define DMODEL  1024
#define NHEAD   16
#define HDIM    64
#define NOUT    3072   // concat Q|K|V output columns

typedef __attribute__((ext_vector_type(8))) short short8v;
typedef __attribute__((ext_vector_type(4))) float f32x4;
typedef __attribute__((ext_vector_type(16))) float f32x16;
typedef __attribute__((ext_vector_type(4))) unsigned short ushort4v;
typedef __attribute__((ext_vector_type(4))) unsigned int u32x4;

static __device__ __forceinline__ void gload_lds16(const void* g, void* l) {
  __builtin_amdgcn_global_load_lds((const __attribute__((address_space(1))) void*)g,
                                   (__attribute__((address_space(3))) void*)l, 16, 0, 0);
}

static __device__ __forceinline__ unsigned cvtpk(float a, float b) {
  unsigned r;
  asm("v_cvt_pk_bf16_f32 %0, %1, %2" : "=v"(r) : "v"(a), "v"(b));
  return r;
}

// ---------- pass 1a: node_emb fp32 -> bf16 ----------
__global__ void cvt_x_kernel(const float* __restrict__ x, __hip_bfloat16* __restrict__ xb) {
  int i = blockIdx.x * blockDim.x + threadIdx.x;
  float4 v = ((const float4*)x)[i];
  union { ushort4v u; __hip_bfloat16 h[4]; } o;
  o.h[0] = __float2bfloat16(v.x);
  o.h[1] = __float2bfloat16(v.y);
  o.h[2] = __float2bfloat16(v.z);
  o.h[3] = __float2bfloat16(v.w);
  ((ushort4v*)xb)[i] = o.u;
}

// ---------- pass 1b: W[in][out] fp32 -> WT[out][in] bf16, vectorized ----------
// block (8,32): phase1 lane loads float4 (4 o-cols), phase2 lane stores ushort4 (4 i's)
__global__ void transpose_w_kernel(const float* __restrict__ Wq, const float* __restrict__ Wk,
                                   const float* __restrict__ Wv, __hip_bfloat16* __restrict__ WT) {
  __shared__ float tile[32][33];
  const float* W = blockIdx.z == 0 ? Wq : (blockIdx.z == 1 ? Wk : Wv);
  int o0 = blockIdx.x * 32, i0 = blockIdx.y * 32;
  int tx = threadIdx.x, ty = threadIdx.y;  // 8 x 32
  {
    float4 v = *(const float4*)&W[(size_t)(i0 + ty) * DMODEL + o0 + tx * 4];
    tile[ty][tx * 4 + 0] = v.x;
    tile[ty][tx * 4 + 1] = v.y;
    tile[ty][tx * 4 + 2] = v.z;
    tile[ty][tx * 4 + 3] = v.w;
  }
  __syncthreads();
  __hip_bfloat16* outp = WT + (size_t)blockIdx.z * DMODEL * DMODEL;
  union { ushort4v u; __hip_bfloat16 h[4]; } o;
#pragma unroll
  for (int c = 0; c < 4; ++c) o.h[c] = __float2bfloat16(tile[tx * 4 + c][ty]);
  *(ushort4v*)&outp[(size_t)(o0 + ty) * DMODEL + i0 + tx * 4] = o.u;
}

// ---------- pass 2: fused QKV GEMM, 128x128x32 ----------
// Q output is pre-scaled by 0.125*log2(e) so attention works in exp2 domain.
__global__ __launch_bounds__(256, 2) void gemm_qkv_kernel(
    const __hip_bfloat16* __restrict__ X, const __hip_bfloat16* __restrict__ WT,
    const float* __restrict__ bq, const float* __restrict__ bk, const float* __restrict__ bv,
    __hip_bfloat16* __restrict__ Qo, __hip_bfloat16* __restrict__ Ko, __hip_bfloat16* __restrict__ Vt) {
  __shared__ __hip_bfloat16 As[128 * 32];
  __shared__ __hip_bfloat16 Bs[128 * 32];
  const int t = threadIdx.x;
  const int lane = t & 63;
  const int w = t >> 6, wr = w >> 1, wc = w & 1;
  const int bm = blockIdx.y, bn = blockIdx.x;

  f32x4 acc[4][4] = {};

  const int rowA = t >> 2;
  const int koff = (t & 3) * 8;
  const __hip_bfloat16* Ag0 = X + (size_t)(bm * 128 + rowA) * DMODEL + koff;
  const __hip_bfloat16* Ag1 = X + (size_t)(bm * 128 + 64 + rowA) * DMODEL + koff;
  const __hip_bfloat16* Bg0 = WT + (size_t)(bn * 128 + rowA) * DMODEL + koff;
  const __hip_bfloat16* Bg1 = WT + (size_t)(bn * 128 + 64 + rowA) * DMODEL + koff;
  __hip_bfloat16* Al0 = &As[t * 8];
  __hip_bfloat16* Al1 = &As[(t + 256) * 8];
  __hip_bfloat16* Bl0 = &Bs[t * 8];
  __hip_bfloat16* Bl1 = &Bs[(t + 256) * 8];

  const short* As_s = (const short*)As;
  const short* Bs_s = (const short*)Bs;
  const int fr = lane & 15, fk = (lane >> 4) * 8;

  for (int kt = 0; kt < DMODEL / 32; ++kt) {
    gload_lds16(Ag0 + kt * 32, Al0);
    gload_lds16(Ag1 + kt * 32, Al1);
    gload_lds16(Bg0 + kt * 32, Bl0);
    gload_lds16(Bg1 + kt * 32, Bl1);
    __syncthreads();
    short8v a[4], b[4];
#pragma unroll
    for (int m = 0; m < 4; ++m)
      a[m] = *(const short8v*)&As_s[(wr * 64 + m * 16 + fr) * 32 + fk];
#pragma unroll
    for (int n = 0; n < 4; ++n)
      b[n] = *(const short8v*)&Bs_s[(wc * 64 + n * 16 + fr) * 32 + fk];
#pragma unroll
    for (int m = 0; m < 4; ++m)
#pragma unroll
      for (int n = 0; n < 4; ++n)
        acc[m][n] = __builtin_amdgcn_mfma_f32_16x16x32_bf16(a[m], b[n], acc[m][n], 0, 0, 0);
    __syncthreads();
  }

  const int row0 = bm * 128 + wr * 64;
  const int col0 = bn * 128 + wc * 64;
  const int which = col0 >> 10;
  const float* bias = which == 0 ? bq : (which == 1 ? bk : bv);
  const float QSCALE = 0.18033688011112042f;  // 0.125 * log2(e)
#pragma unroll
  for (int m = 0; m < 4; ++m) {
#pragma unroll
    for (int n = 0; n < 4; ++n) {
#pragma unroll
      for (int i = 0; i < 4; ++i) {
        int r = row0 + m * 16 + (lane >> 4) * 4 + i;
        int c = col0 + n * 16 + (lane & 15);
        int oo = c & 1023;
        float v = acc[m][n][i] + bias[oo];
        if (which == 0) v *= QSCALE;
        int h = oo >> 6, d = oo & 63;
        __hip_bfloat16 hv = __float2bfloat16(v);
        if (which == 0)      Qo[((size_t)h << 18) + r * 64 + d] = hv;
        else if (which == 1) Ko[((size_t)h << 18) + r * 64 + d] = hv;
        else                 Vt[((size_t)h << 18) + d * 4096 + r] = hv;
      }
    }
  }
}

// ---------- pass 3: flash attention, 64 q-rows/wave, 2-tile barrier intervals ----------
// 4-buffer LDS (2 pairs x 2 tiles); stage 2 tiles while computing 2 -> half the
// barriers of R9, and no setprio/phase fences so the scheduler can hide softmax
// VALU of one tile/q-block under MFMAs of the other. NSPLIT=2, grid 512.
__global__ __launch_bounds__(256, 2) void attn64_kernel(
    const __hip_bfloat16* __restrict__ Q, const __hip_bfloat16* __restrict__ K,
    const __hip_bfloat16* __restrict__ Vt,
    __hip_bfloat16* __restrict__ Opart, float* __restrict__ lpart) {
  __shared__ __align__(16) short lds_k[2][2][64 * 64];
  __shared__ __align__(16) short lds_v[2][2][64 * 64];

  // 512 blocks; XCD-bijective; 64 consecutive lin per XCD = 2 heads L2-resident
  const int bid = blockIdx.x;
  const int lin = (bid & 7) * 64 + (bid >> 3);
  const int h = lin >> 5, qb = (lin & 31) >> 1, split = lin & 1;

  const int t = threadIdx.x, lane = t & 63, w = t >> 6;
  const int lq = lane & 31, hi = lane >> 5;

  const short* Qh = (const short*)Q + ((size_t)h << 18);
  const short* Kh = (const short*)K + ((size_t)h << 18);
  const short* Vh = (const short*)Vt + ((size_t)h << 18);

  const int q0 = qb * 256 + w * 64;

  // Q B-fragments for both q-blocks: lane holds Q[q][kk*16 + hi*8 .. +8]
  short8v qfA[4], qfB[4];
#pragma unroll
  for (int kk = 0; kk < 4; ++kk) {
    qfA[kk] = *(const short8v*)&Qh[(q0 + lq) * 64 + kk * 16 + hi * 8];
    qfB[kk] = *(const short8v*)&Qh[(q0 + 32 + lq) * 64 + kk * 16 + hi * 8];
  }

  // XOR-swizzled ds_read offsets (elements): row = half*32+lq, chunk = kk*2+hi
  int off8[2][4];
#pragma unroll
  for (int half = 0; half < 2; ++half)
#pragma unroll
    for (int kk = 0; kk < 4; ++kk)
      off8[half][kk] = (half * 32 + lq) * 64 + (((kk * 2 + hi) ^ (lq & 7)) * 8);

  // staging: 4 gload_lds (2 K + 2 V) per tile per thread; pre-swizzled global src
  auto stage = [&](int kt, int p, int s) {
#pragma unroll
    for (int i = 0; i < 2; ++i) {
      int c = w * 128 + i * 64 + lane;
      int row = c >> 3, ss = (c & 7) ^ (row & 7);
      gload_lds16(Kh + (size_t)(kt * 64 + row) * 64 + ss * 8, &lds_k[p][s][c * 8]);
    }
#pragma unroll
    for (int i = 0; i < 2; ++i) {
      int c = w * 128 + i * 64 + lane;
      int row = c >> 3, ss = (c & 7) ^ (row & 7);
      gload_lds16(Vh + (size_t)row * 4096 + kt * 64 + ss * 8, &lds_v[p][s][c * 8]);
    }
  };

  f32x16 oA0 = {}, oA1 = {}, oB0 = {}, oB1 = {};
  float lA_r = 0.f, lB_r = 0.f;

  // one tile's full chain: QK^T -> exp2/pack -> PV accumulate
  auto compute = [&](const short* kp, const short* vp) {
    f32x16 sA0 = {}, sA1 = {}, sB0 = {}, sB1 = {};
#pragma unroll
    for (int kk = 0; kk < 4; ++kk) {
      short8v ka0 = *(const short8v*)&kp[off8[0][kk]];
      sA0 = __builtin_amdgcn_mfma_f32_32x32x16_bf16(ka0, qfA[kk], sA0, 0, 0, 0);
      sB0 = __builtin_amdgcn_mfma_f32_32x32x16_bf16(ka0, qfB[kk], sB0, 0, 0, 0);
      short8v ka1 = *(const short8v*)&kp[off8[1][kk]];
      sA1 = __builtin_amdgcn_mfma_f32_32x32x16_bf16(ka1, qfA[kk], sA1, 0, 0, 0);
      sB1 = __builtin_amdgcn_mfma_f32_32x32x16_bf16(ka1, qfB[kk], sB1, 0, 0, 0);
    }
    short8v paA[4], paB[4];
#pragma unroll
    for (int j = 0; j < 16; ++j) { sA0[j] = __builtin_amdgcn_exp2f(sA0[j]); lA_r += sA0[j]; }
#pragma unroll
    for (int j = 0; j < 16; ++j) { sA1[j] = __builtin_amdgcn_exp2f(sA1[j]); lA_r += sA1[j]; }
#pragma unroll
    for (int half = 0; half < 2; ++half) {
      const f32x16& s = half ? sA1 : sA0;
#pragma unroll
      for (int g = 0; g < 2; ++g) {
        unsigned a0 = cvtpk(s[g * 8 + 0], s[g * 8 + 1]), a1 = cvtpk(s[g * 8 + 2], s[g * 8 + 3]);
        unsigned b0 = cvtpk(s[g * 8 + 4], s[g * 8 + 5]), b1 = cvtpk(s[g * 8 + 6], s[g * 8 + 7]);
        asm volatile("v_permlane32_swap_b32 %0, %1" : "+v"(a0), "+v"(b0));
        asm volatile("v_permlane32_swap_b32 %0, %1" : "+v"(a1), "+v"(b1));
        u32x4 u = {a0, a1, b0, b1};
        paA[half * 2 + g] = __builtin_bit_cast(short8v, u);
      }
    }
#pragma unroll
    for (int j = 0; j < 16; ++j) { sB0[j] = __builtin_amdgcn_exp2f(sB0[j]); lB_r += sB0[j]; }
#pragma unroll
    for (int j = 0; j < 16; ++j) { sB1[j] = __builtin_amdgcn_exp2f(sB1[j]); lB_r += sB1[j]; }
#pragma unroll
    for (int half = 0; half < 2; ++half) {
      const f32x16& s = half ? sB1 : sB0;
#pragma unroll
      for (int g = 0; g < 2; ++g) {
        unsigned a0 = cvtpk(s[g * 8 + 0], s[g * 8 + 1]), a1 = cvtpk(s[g * 8 + 2], s[g * 8 + 3]);
        unsigned b0 = cvtpk(s[g * 8 + 4], s[g * 8 + 5]), b1 = cvtpk(s[g * 8 + 6], s[g * 8 + 7]);
        asm volatile("v_permlane32_swap_b32 %0, %1" : "+v"(a0), "+v"(b0));
        asm volatile("v_permlane32_swap_b32 %0, %1" : "+v"(a1), "+v"(b1));
        u32x4 u = {a0, a1, b0, b1};
        paB[half * 2 + g] = __builtin_bit_cast(short8v, u);
      }
    }
#pragma unroll
    for (int kk = 0; kk < 4; ++kk) {
      short8v vb0 = *(const short8v*)&vp[off8[0][kk]];
      oA0 = __builtin_amdgcn_mfma_f32_32x32x16_bf16(paA[kk], vb0, oA0, 0, 0, 0);
      oB0 = __builtin_amdgcn_mfma_f32_32x32x16_bf16(paB[kk], vb0, oB0, 0, 0, 0);
      short8v vb1 = *(const short8v*)&vp[off8[1][kk]];
      oA1 = __builtin_amdgcn_mfma_f32_32x32x16_bf16(paA[kk], vb1, oA1, 0, 0, 0);
      oB1 = __builtin_amdgcn_mfma_f32_32x32x16_bf16(paB[kk], vb1, oB1, 0, 0, 0);
    }
  };

  const int NT = 32;           // tiles per block (NSPLIT=2)
  const int NIV = NT / 2;      // 2-tile intervals
  const int kt0 = split * NT;

  stage(kt0 + 0, 0, 0);
  stage(kt0 + 1, 0, 1);

  for (int iv = 0; iv < NIV; ++iv) {
    const int p = iv & 1;
    __builtin_amdgcn_s_barrier();  // B1: all waves done reading pair p^1
    if (iv + 1 < NIV) {
      stage(kt0 + 2 * iv + 2, p ^ 1, 0);
      stage(kt0 + 2 * iv + 3, p ^ 1, 1);
      asm volatile("s_waitcnt vmcnt(8)" ::: "memory");  // pair p landed, p^1 in flight
    } else {
      asm volatile("s_waitcnt vmcnt(0)" ::: "memory");
    }
    __builtin_amdgcn_s_barrier();  // B2: pair p staged by all waves
    __builtin_amdgcn_sched_barrier(0);  // pin ds_reads below B2
    compute(lds_k[p][0], lds_v[p][0]);
    compute(lds_k[p][1], lds_v[p][1]);
  }

  // epilogue: unnormalized bf16 O partials + fp32 l partials
  {
    float lA = lA_r + __shfl_xor(lA_r, 32);
    float lB = lB_r + __shfl_xor(lB_r, 32);
    if (hi == 0) {
      lpart[((split * NHEAD + h) << 12) + q0 + lq] = lA;
      lpart[((split * NHEAD + h) << 12) + q0 + 32 + lq] = lB;
    }
    __hip_bfloat16* Op = Opart + (size_t)split * N_NODES * DMODEL;
#pragma unroll
    for (int r = 0; r < 16; ++r) {
      int ql = (r & 3) + 8 * (r >> 2) + 4 * hi;
      int qgA = q0 + ql, qgB = q0 + 32 + ql;
      Op[(size_t)qgA * DMODEL + (h << 6) + lq] = __float2bfloat16(oA0[r]);
      Op[(size_t)qgA * DMODEL + (h << 6) + 32 + lq] = __float2bfloat16(oA1[r]);
      Op[(size_t)qgB * DMODEL + (h << 6) + lq] = __float2bfloat16(oB0[r]);
      Op[(size_t)qgB * DMODEL + (h << 6) + 32 + lq] = __float2bfloat16(oB1[r]);
    }
  }
}

// ---------- pass 4: out = (O0 + O1) / (l0 + l1), bf16 partials ----------
__global__ void combine_kernel(const __hip_bfloat16* __restrict__ Opart,
                               const float* __restrict__ lpart,
                               float* __restrict__ out) {
  int idx = blockIdx.x * 256 + threadIdx.x;  // one f32x4 (4 outputs)
  int n = idx >> 8;
  int c4 = idx & 255;
  int h = c4 >> 4;
  float l0 = lpart[(h << 12) + n];
  float l1 = lpart[(NHEAD << 12) + (h << 12) + n];
  float inv = 1.0f / (l0 + l1);
  ushort4v a = ((const ushort4v*)Opart)[idx];
  ushort4v b = ((const ushort4v*)(Opart + (size_t)N_NODES * DMODEL))[idx];
  f32x4 o;
#pragma unroll
  for (int j = 0; j < 4; ++j) {
    float fa = __uint_as_float((unsigned)(unsigned short)a[j] << 16);
    float fb = __uint_as_float((unsigned)(unsigned short)b[j] << 16);
    o[j] = (fa + fb) * inv;
  }
  ((f32x4*)out)[idx] = o;
}

// ---------- fallback (ws too small): single-pass 32q/wave ----------
__global__ __launch_bounds__(256, 2) void attn_single_kernel(
    const __hip_bfloat16* __restrict__ Q, const __hip_bfloat16* __restrict__ K,
    const __hip_bfloat16* __restrict__ Vt, float* __restrict__ out) {
  __shared__ __align__(16) short lds_k[2][64 * 64];
  __shared__ __align__(16) short lds_v[2][64 * 64];
  __shared__ float smc[4][32];
  const int bid = blockIdx.x;
  const int lin = (bid & 7) * 64 + (bid >> 3);
  const int h = lin >> 5, qb = lin & 31;
  const int t = threadIdx.x, lane = t & 63, w = t >> 6;
  const int lq = lane & 31, hi = lane >> 5;
  const short* Qh = (const short*)Q + ((size_t)h << 18);
  const short* Kh = (const short*)K + ((size_t)h << 18);
  const short* Vh = (const short*)Vt + ((size_t)h << 18);
  const int q0 = qb * 128 + w * 32;
  short8v qf[4];
#pragma unroll
  for (int kk = 0; kk < 4; ++kk)
    qf[kk] = *(const short8v*)&Qh[(q0 + lq) * 64 + kk * 16 + hi * 8];
  int off8[2][4];
#pragma unroll
  for (int half = 0; half < 2; ++half)
#pragma unroll
    for (int kk = 0; kk < 4; ++kk)
      off8[half][kk] = (half * 32 + lq) * 64 + (((kk * 2 + hi) ^ (lq & 7)) * 8);
  auto stage = [&](int kt, int b) {
#pragma unroll
    for (int i = 0; i < 2; ++i) {
      int c = w * 128 + i * 64 + lane;
      int row = c >> 3, ss = (c & 7) ^ (row & 7);
      gload_lds16(Kh + (size_t)(kt * 64 + row) * 64 + ss * 8, &lds_k[b][c * 8]);
    }
#pragma unroll
    for (int i = 0; i < 2; ++i) {
      int c = w * 128 + i * 64 + lane;
      int row = c >> 3, ss = (c & 7) ^ (row & 7);
      gload_lds16(Vh + (size_t)row * 4096 + kt * 64 + ss * 8, &lds_v[b][c * 8]);
    }
  };
  f32x16 o0 = {}, o1 = {};
  float l_r = 0.f;
  stage(0, 0);
  for (int kt = 0; kt < 64; ++kt) {
    const int cur = kt & 1;
    __builtin_amdgcn_s_barrier();
    if (kt + 1 < 64) {
      stage(kt + 1, cur ^ 1);
      asm volatile("s_waitcnt vmcnt(4)" ::: "memory");
    } else {
      asm volatile("s_waitcnt vmcnt(0)" ::: "memory");
    }
    __builtin_amdgcn_s_barrier();
    __builtin_amdgcn_sched_barrier(0);
    const short* kp = lds_k[cur];
    const short* vp = lds_v[cur];
    f32x16 s0 = {}, s1 = {};
#pragma unroll
    for (int kk = 0; kk < 4; ++kk) {
      short8v ka0 = *(const short8v*)&kp[off8[0][kk]];
      s0 = __builtin_amdgcn_mfma_f32_32x32x16_bf16(ka0, qf[kk], s0, 0, 0, 0);
      short8v ka1 = *(const short8v*)&kp[off8[1][kk]];
      s1 = __builtin_amdgcn_mfma_f32_32x32x16_bf16(ka1, qf[kk], s1, 0, 0, 0);
    }
#pragma unroll
    for (int j = 0; j < 16; ++j) { s0[j] = __builtin_amdgcn_exp2f(s0[j]); l_r += s0[j]; }
#pragma unroll
    for (int j = 0; j < 16; ++j) { s1[j] = __builtin_amdgcn_exp2f(s1[j]); l_r += s1[j]; }
    short8v pa[4];
#pragma unroll
    for (int half = 0; half < 2; ++half) {
      const f32x16& s = half ? s1 : s0;
#pragma unroll
      for (int g = 0; g < 2; ++g) {
        unsigned a0 = cvtpk(s[g * 8 + 0], s[g * 8 + 1]), a1 = cvtpk(s[g * 8 + 2], s[g * 8 + 3]);
        unsigned b0 = cvtpk(s[g * 8 + 4], s[g * 8 + 5]), b1 = cvtpk(s[g * 8 + 6], s[g * 8 + 7]);
        asm volatile("v_permlane32_swap_b32 %0, %1" : "+v"(a0), "+v"(b0));
        asm volatile("v_permlane32_swap_b32 %0, %1" : "+v"(a1), "+v"(b1));
        u32x4 u = {a0, a1, b0, b1};
        pa[half * 2 + g] = __builtin_bit_cast(short8v, u);
      }
    }
#pragma unroll
    for (int kk = 0; kk < 4; ++kk) {
      short8v vb0 = *(const short8v*)&vp[off8[0][kk]];
      o0 = __builtin_amdgcn_mfma_f32_32x32x16_bf16(pa[kk], vb0, o0, 0, 0, 0);
      short8v vb1 = *(const short8v*)&vp[off8[1][kk]];
      o1 = __builtin_amdgcn_mfma_f32_32x32x16_bf16(pa[kk], vb1, o1, 0, 0, 0);
    }
  }
  {
    float lt = l_r + __shfl_xor(l_r, 32);
    float inv = 1.0f / lt;
    if (lane < 32) smc[w][lq] = inv;
#pragma unroll
    for (int r = 0; r < 16; ++r) {
      int ql = (r & 3) + 8 * (r >> 2) + 4 * hi;
      float iv = smc[w][ql];
      int qg = q0 + ql;
      out[(size_t)qg * DMODEL + (h << 6) + lq] = o0[r] * iv;
      out[(size_t)qg * DMODEL + (h << 6) + 32 + lq] = o1[r] * iv;
    }
  }
}

extern "C" void kernel_launch(void* const* d_in, const int* in_sizes, int n_in,
                              void* d_out, int out_size, void* d_ws, size_t ws_size,
                              hipStream_t stream) {
  const float* node_emb = (const float*)d_in[0];
  const float* Wq = (const float*)d_in[1];
  const float* bq = (const float*)d_in[2];
  const float* Wk = (const float*)d_in[3];
  const float* bk = (const float*)d_in[4];
  const float* Wv = (const float*)d_in[5];
  const float* bv = (const float*)d_in[6];
  float* out = (float*)d_out;

  // ws layout: [Qb|Kb|Vtb live through attn][Xbf|WT dead after GEMM -> Opart/lpart overlay]
  const size_t HSZ = (size_t)NHEAD * N_NODES * HDIM;  // per-matrix elems (4.19M)
  __hip_bfloat16* Qb  = (__hip_bfloat16*)d_ws;
  __hip_bfloat16* Kb  = Qb + HSZ;
  __hip_bfloat16* Vtb = Kb + HSZ;
  __hip_bfloat16* Xbf = Vtb + HSZ;
  __hip_bfloat16* WT  = Xbf + (size_t)N_NODES * DMODEL;

  __hip_bfloat16* Opart = Xbf;  // overlays Xbf/WT (dead after GEMM)
  float* lpart = (float*)(Opart + 2 * (size_t)N_NODES * DMODEL);

  const size_t split_bytes =
      (3 * HSZ + 2 * (size_t)N_NODES * DMODEL) * sizeof(__hip_bfloat16) +
      2 * (size_t)NHEAD * N_NODES * sizeof(float);
  const size_t base_bytes =
      (3 * HSZ + (size_t)N_NODES * DMODEL + (size_t)NOUT * DMODEL) * sizeof(__hip_bfloat16);
  const bool can_split = ws_size >= (split_bytes > base_bytes ? split_bytes : base_bytes);

  cvt_x_kernel<<<(N_NODES * DMODEL) / (256 * 4), 256, 0, stream>>>(node_emb, Xbf);
  transpose_w_kernel<<<dim3(32, 32, 3), dim3(8, 32), 0, stream>>>(Wq, Wk, Wv, WT);
  gemm_qkv_kernel<<<dim3(NOUT / 128, N_NODES / 128), 256, 0, stream>>>(
      Xbf, WT, bq, bk, bv, Qb, Kb, Vtb);

  if (can_split) {
    attn64_kernel<<<512, 256, 0, stream>>>(Qb, Kb, Vtb, Opart, lpart);
    combine_kernel<<<(N_NODES * DMODEL) / (256 * 4), 256, 0, stream>>>(Opart, lpart, out);
  } else {
    attn_single_kernel<<<512, 256, 0, stream>>>(Qb, Kb, Vtb, out);
  }
}

// Round 11
// 131.529 us; speedup vs baseline: 3.4441x; 1.0226x over previous
//
#include <hip/hip_runtime.h>
#include <hip/hip_bf16.h>

#define N_NODES 4096
#define DMODEL  1024
#define NHEAD   16
#define HDIM    64
#define NOUT    3072   // concat Q|K|V output columns

typedef __attribute__((ext_vector_type(8))) short short8v;
typedef __attribute__((ext_vector_type(4))) float f32x4;
typedef __attribute__((ext_vector_type(16))) float f32x16;
typedef __attribute__((ext_vector_type(4))) unsigned short ushort4v;
typedef __attribute__((ext_vector_type(4))) unsigned int u32x4;

static __device__ __forceinline__ void gload_lds16(const void* g, void* l) {
  __builtin_amdgcn_global_load_lds((const __attribute__((address_space(1))) void*)g,
                                   (__attribute__((address_space(3))) void*)l, 16, 0, 0);
}

static __device__ __forceinline__ unsigned cvtpk(float a, float b) {
  unsigned r;
  asm("v_cvt_pk_bf16_f32 %0, %1, %2" : "=v"(r) : "v"(a), "v"(b));
  return r;
}

// ---------- pass 1 (fused): node_emb fp32->bf16  +  W transpose->bf16 ----------
// blocks [0,4096): cvt X (256 float4/block). blocks [4096,7168): W transpose.
// Branch is uniform per block (blockIdx), so __syncthreads in branch is safe.
__global__ void prep_kernel(const float* __restrict__ x, __hip_bfloat16* __restrict__ xb,
                            const float* __restrict__ Wq, const float* __restrict__ Wk,
                            const float* __restrict__ Wv, __hip_bfloat16* __restrict__ WT) {
  __shared__ float tile[32][33];
  const int bid = blockIdx.x;
  const int t = threadIdx.x;
  if (bid < 4096) {
    int i = bid * 256 + t;
    float4 v = ((const float4*)x)[i];
    union { ushort4v u; __hip_bfloat16 h[4]; } o;
    o.h[0] = __float2bfloat16(v.x);
    o.h[1] = __float2bfloat16(v.y);
    o.h[2] = __float2bfloat16(v.z);
    o.h[3] = __float2bfloat16(v.w);
    ((ushort4v*)xb)[i] = o.u;
  } else {
    int b2 = bid - 4096;
    int z = b2 >> 10, rem = b2 & 1023;
    int bx = rem & 31, by = rem >> 5;
    const float* W = z == 0 ? Wq : (z == 1 ? Wk : Wv);
    int o0 = bx * 32, i0 = by * 32;
    int tx = t & 7, ty = t >> 3;  // 8 x 32
    {
      float4 v = *(const float4*)&W[(size_t)(i0 + ty) * DMODEL + o0 + tx * 4];
      tile[ty][tx * 4 + 0] = v.x;
      tile[ty][tx * 4 + 1] = v.y;
      tile[ty][tx * 4 + 2] = v.z;
      tile[ty][tx * 4 + 3] = v.w;
    }
    __syncthreads();
    __hip_bfloat16* outp = WT + (size_t)z * DMODEL * DMODEL;
    union { ushort4v u; __hip_bfloat16 h[4]; } o;
#pragma unroll
    for (int c = 0; c < 4; ++c) o.h[c] = __float2bfloat16(tile[tx * 4 + c][ty]);
    *(ushort4v*)&outp[(size_t)(o0 + ty) * DMODEL + i0 + tx * 4] = o.u;
  }
}

// ---------- pass 2: fused QKV GEMM, 128x128x32, counted-vmcnt double-buffer ----------
// Q output is pre-scaled by 0.125*log2(e) so attention works in exp2 domain.
// Loop mirrors the attn kernel's proven pattern: B1 -> stage(t+1) -> vmcnt(4)
// -> B2 -> compute. Next tile's loads stay in flight across the barrier
// (no full drain as with __syncthreads).
__global__ __launch_bounds__(256, 2) void gemm_qkv_kernel(
    const __hip_bfloat16* __restrict__ X, const __hip_bfloat16* __restrict__ WT,
    const float* __restrict__ bq, const float* __restrict__ bk, const float* __restrict__ bv,
    __hip_bfloat16* __restrict__ Qo, __hip_bfloat16* __restrict__ Ko, __hip_bfloat16* __restrict__ Vt) {
  __shared__ __hip_bfloat16 As[2][128 * 32];
  __shared__ __hip_bfloat16 Bs[2][128 * 32];
  const int t = threadIdx.x;
  const int lane = t & 63;
  const int w = t >> 6, wr = w >> 1, wc = w & 1;
  const int bm = blockIdx.y, bn = blockIdx.x;

  f32x4 acc[4][4] = {};

  const int rowA = t >> 2;
  const int koff = (t & 3) * 8;
  const __hip_bfloat16* Ag0 = X + (size_t)(bm * 128 + rowA) * DMODEL + koff;
  const __hip_bfloat16* Ag1 = X + (size_t)(bm * 128 + 64 + rowA) * DMODEL + koff;
  const __hip_bfloat16* Bg0 = WT + (size_t)(bn * 128 + rowA) * DMODEL + koff;
  const __hip_bfloat16* Bg1 = WT + (size_t)(bn * 128 + 64 + rowA) * DMODEL + koff;

  auto stage = [&](int kt, int b) {
    gload_lds16(Ag0 + kt * 32, &As[b][t * 8]);
    gload_lds16(Ag1 + kt * 32, &As[b][(t + 256) * 8]);
    gload_lds16(Bg0 + kt * 32, &Bs[b][t * 8]);
    gload_lds16(Bg1 + kt * 32, &Bs[b][(t + 256) * 8]);
  };

  const int fr = lane & 15, fk = (lane >> 4) * 8;

  stage(0, 0);

  for (int kt = 0; kt < DMODEL / 32; ++kt) {
    const int cur = kt & 1;
    __builtin_amdgcn_s_barrier();  // B1: all waves done reading buf cur^1
    if (kt + 1 < DMODEL / 32) {
      stage(kt + 1, cur ^ 1);
      asm volatile("s_waitcnt vmcnt(4)" ::: "memory");  // cur tile landed, next in flight
    } else {
      asm volatile("s_waitcnt vmcnt(0)" ::: "memory");
    }
    __builtin_amdgcn_s_barrier();  // B2: buf cur staged by all waves
    __builtin_amdgcn_sched_barrier(0);  // pin ds_reads below B2

    const short* As_s = (const short*)As[cur];
    const short* Bs_s = (const short*)Bs[cur];
    short8v a[4], b[4];
#pragma unroll
    for (int m = 0; m < 4; ++m)
      a[m] = *(const short8v*)&As_s[(wr * 64 + m * 16 + fr) * 32 + fk];
#pragma unroll
    for (int n = 0; n < 4; ++n)
      b[n] = *(const short8v*)&Bs_s[(wc * 64 + n * 16 + fr) * 32 + fk];
#pragma unroll
    for (int m = 0; m < 4; ++m)
#pragma unroll
      for (int n = 0; n < 4; ++n)
        acc[m][n] = __builtin_amdgcn_mfma_f32_16x16x32_bf16(a[m], b[n], acc[m][n], 0, 0, 0);
  }

  const int row0 = bm * 128 + wr * 64;
  const int col0 = bn * 128 + wc * 64;
  const int which = col0 >> 10;
  const float* bias = which == 0 ? bq : (which == 1 ? bk : bv);
  const float QSCALE = 0.18033688011112042f;  // 0.125 * log2(e)
#pragma unroll
  for (int m = 0; m < 4; ++m) {
#pragma unroll
    for (int n = 0; n < 4; ++n) {
#pragma unroll
      for (int i = 0; i < 4; ++i) {
        int r = row0 + m * 16 + (lane >> 4) * 4 + i;
        int c = col0 + n * 16 + (lane & 15);
        int oo = c & 1023;
        float v = acc[m][n][i] + bias[oo];
        if (which == 0) v *= QSCALE;
        int h = oo >> 6, d = oo & 63;
        __hip_bfloat16 hv = __float2bfloat16(v);
        if (which == 0)      Qo[((size_t)h << 18) + r * 64 + d] = hv;
        else if (which == 1) Ko[((size_t)h << 18) + r * 64 + d] = hv;
        else                 Vt[((size_t)h << 18) + d * 4096 + r] = hv;
      }
    }
  }
}

// ---------- pass 3: flash attention, 64 q-rows/wave, 2-tile barrier intervals ----------
// (unchanged from R10 — structural local optimum at ~85 us; see session notes)
__global__ __launch_bounds__(256, 2) void attn64_kernel(
    const __hip_bfloat16* __restrict__ Q, const __hip_bfloat16* __restrict__ K,
    const __hip_bfloat16* __restrict__ Vt,
    __hip_bfloat16* __restrict__ Opart, float* __restrict__ lpart) {
  __shared__ __align__(16) short lds_k[2][2][64 * 64];
  __shared__ __align__(16) short lds_v[2][2][64 * 64];

  const int bid = blockIdx.x;
  const int lin = (bid & 7) * 64 + (bid >> 3);
  const int h = lin >> 5, qb = (lin & 31) >> 1, split = lin & 1;

  const int t = threadIdx.x, lane = t & 63, w = t >> 6;
  const int lq = lane & 31, hi = lane >> 5;

  const short* Qh = (const short*)Q + ((size_t)h << 18);
  const short* Kh = (const short*)K + ((size_t)h << 18);
  const short* Vh = (const short*)Vt + ((size_t)h << 18);

  const int q0 = qb * 256 + w * 64;

  short8v qfA[4], qfB[4];
#pragma unroll
  for (int kk = 0; kk < 4; ++kk) {
    qfA[kk] = *(const short8v*)&Qh[(q0 + lq) * 64 + kk * 16 + hi * 8];
    qfB[kk] = *(const short8v*)&Qh[(q0 + 32 + lq) * 64 + kk * 16 + hi * 8];
  }

  int off8[2][4];
#pragma unroll
  for (int half = 0; half < 2; ++half)
#pragma unroll
    for (int kk = 0; kk < 4; ++kk)
      off8[half][kk] = (half * 32 + lq) * 64 + (((kk * 2 + hi) ^ (lq & 7)) * 8);

  auto stage = [&](int kt, int p, int s) {
#pragma unroll
    for (int i = 0; i < 2; ++i) {
      int c = w * 128 + i * 64 + lane;
      int row = c >> 3, ss = (c & 7) ^ (row & 7);
      gload_lds16(Kh + (size_t)(kt * 64 + row) * 64 + ss * 8, &lds_k[p][s][c * 8]);
    }
#pragma unroll
    for (int i = 0; i < 2; ++i) {
      int c = w * 128 + i * 64 + lane;
      int row = c >> 3, ss = (c & 7) ^ (row & 7);
      gload_lds16(Vh + (size_t)row * 4096 + kt * 64 + ss * 8, &lds_v[p][s][c * 8]);
    }
  };

  f32x16 oA0 = {}, oA1 = {}, oB0 = {}, oB1 = {};
  float lA_r = 0.f, lB_r = 0.f;

  auto compute = [&](const short* kp, const short* vp) {
    f32x16 sA0 = {}, sA1 = {}, sB0 = {}, sB1 = {};
#pragma unroll
    for (int kk = 0; kk < 4; ++kk) {
      short8v ka0 = *(const short8v*)&kp[off8[0][kk]];
      sA0 = __builtin_amdgcn_mfma_f32_32x32x16_bf16(ka0, qfA[kk], sA0, 0, 0, 0);
      sB0 = __builtin_amdgcn_mfma_f32_32x32x16_bf16(ka0, qfB[kk], sB0, 0, 0, 0);
      short8v ka1 = *(const short8v*)&kp[off8[1][kk]];
      sA1 = __builtin_amdgcn_mfma_f32_32x32x16_bf16(ka1, qfA[kk], sA1, 0, 0, 0);
      sB1 = __builtin_amdgcn_mfma_f32_32x32x16_bf16(ka1, qfB[kk], sB1, 0, 0, 0);
    }
    short8v paA[4], paB[4];
#pragma unroll
    for (int j = 0; j < 16; ++j) { sA0[j] = __builtin_amdgcn_exp2f(sA0[j]); lA_r += sA0[j]; }
#pragma unroll
    for (int j = 0; j < 16; ++j) { sA1[j] = __builtin_amdgcn_exp2f(sA1[j]); lA_r += sA1[j]; }
#pragma unroll
    for (int half = 0; half < 2; ++half) {
      const f32x16& s = half ? sA1 : sA0;
#pragma unroll
      for (int g = 0; g < 2; ++g) {
        unsigned a0 = cvtpk(s[g * 8 + 0], s[g * 8 + 1]), a1 = cvtpk(s[g * 8 + 2], s[g * 8 + 3]);
        unsigned b0 = cvtpk(s[g * 8 + 4], s[g * 8 + 5]), b1 = cvtpk(s[g * 8 + 6], s[g * 8 + 7]);
        asm volatile("v_permlane32_swap_b32 %0, %1" : "+v"(a0), "+v"(b0));
        asm volatile("v_permlane32_swap_b32 %0, %1" : "+v"(a1), "+v"(b1));
        u32x4 u = {a0, a1, b0, b1};
        paA[half * 2 + g] = __builtin_bit_cast(short8v, u);
      }
    }
#pragma unroll
    for (int j = 0; j < 16; ++j) { sB0[j] = __builtin_amdgcn_exp2f(sB0[j]); lB_r += sB0[j]; }
#pragma unroll
    for (int j = 0; j < 16; ++j) { sB1[j] = __builtin_amdgcn_exp2f(sB1[j]); lB_r += sB1[j]; }
#pragma unroll
    for (int half = 0; half < 2; ++half) {
      const f32x16& s = half ? sB1 : sB0;
#pragma unroll
      for (int g = 0; g < 2; ++g) {
        unsigned a0 = cvtpk(s[g * 8 + 0], s[g * 8 + 1]), a1 = cvtpk(s[g * 8 + 2], s[g * 8 + 3]);
        unsigned b0 = cvtpk(s[g * 8 + 4], s[g * 8 + 5]), b1 = cvtpk(s[g * 8 + 6], s[g * 8 + 7]);
        asm volatile("v_permlane32_swap_b32 %0, %1" : "+v"(a0), "+v"(b0));
        asm volatile("v_permlane32_swap_b32 %0, %1" : "+v"(a1), "+v"(b1));
        u32x4 u = {a0, a1, b0, b1};
        paB[half * 2 + g] = __builtin_bit_cast(short8v, u);
      }
    }
#pragma unroll
    for (int kk = 0; kk < 4; ++kk) {
      short8v vb0 = *(const short8v*)&vp[off8[0][kk]];
      oA0 = __builtin_amdgcn_mfma_f32_32x32x16_bf16(paA[kk], vb0, oA0, 0, 0, 0);
      oB0 = __builtin_amdgcn_mfma_f32_32x32x16_bf16(paB[kk], vb0, oB0, 0, 0, 0);
      short8v vb1 = *(const short8v*)&vp[off8[1][kk]];
      oA1 = __builtin_amdgcn_mfma_f32_32x32x16_bf16(paA[kk], vb1, oA1, 0, 0, 0);
      oB1 = __builtin_amdgcn_mfma_f32_32x32x16_bf16(paB[kk], vb1, oB1, 0, 0, 0);
    }
  };

  const int NT = 32;
  const int NIV = NT / 2;
  const int kt0 = split * NT;

  stage(kt0 + 0, 0, 0);
  stage(kt0 + 1, 0, 1);

  for (int iv = 0; iv < NIV; ++iv) {
    const int p = iv & 1;
    __builtin_amdgcn_s_barrier();
    if (iv + 1 < NIV) {
      stage(kt0 + 2 * iv + 2, p ^ 1, 0);
      stage(kt0 + 2 * iv + 3, p ^ 1, 1);
      asm volatile("s_waitcnt vmcnt(8)" ::: "memory");
    } else {
      asm volatile("s_waitcnt vmcnt(0)" ::: "memory");
    }
    __builtin_amdgcn_s_barrier();
    __builtin_amdgcn_sched_barrier(0);
    compute(lds_k[p][0], lds_v[p][0]);
    compute(lds_k[p][1], lds_v[p][1]);
  }

  {
    float lA = lA_r + __shfl_xor(lA_r, 32);
    float lB = lB_r + __shfl_xor(lB_r, 32);
    if (hi == 0) {
      lpart[((split * NHEAD + h) << 12) + q0 + lq] = lA;
      lpart[((split * NHEAD + h) << 12) + q0 + 32 + lq] = lB;
    }
    __hip_bfloat16* Op = Opart + (size_t)split * N_NODES * DMODEL;
#pragma unroll
    for (int r = 0; r < 16; ++r) {
      int ql = (r & 3) + 8 * (r >> 2) + 4 * hi;
      int qgA = q0 + ql, qgB = q0 + 32 + ql;
      Op[(size_t)qgA * DMODEL + (h << 6) + lq] = __float2bfloat16(oA0[r]);
      Op[(size_t)qgA * DMODEL + (h << 6) + 32 + lq] = __float2bfloat16(oA1[r]);
      Op[(size_t)qgB * DMODEL + (h << 6) + lq] = __float2bfloat16(oB0[r]);
      Op[(size_t)qgB * DMODEL + (h << 6) + 32 + lq] = __float2bfloat16(oB1[r]);
    }
  }
}

// ---------- pass 4: out = (O0 + O1) / (l0 + l1), bf16 partials ----------
__global__ void combine_kernel(const __hip_bfloat16* __restrict__ Opart,
                               const float* __restrict__ lpart,
                               float* __restrict__ out) {
  int idx = blockIdx.x * 256 + threadIdx.x;
  int n = idx >> 8;
  int c4 = idx & 255;
  int h = c4 >> 4;
  float l0 = lpart[(h << 12) + n];
  float l1 = lpart[(NHEAD << 12) + (h << 12) + n];
  float inv = 1.0f / (l0 + l1);
  ushort4v a = ((const ushort4v*)Opart)[idx];
  ushort4v b = ((const ushort4v*)(Opart + (size_t)N_NODES * DMODEL))[idx];
  f32x4 o;
#pragma unroll
  for (int j = 0; j < 4; ++j) {
    float fa = __uint_as_float((unsigned)(unsigned short)a[j] << 16);
    float fb = __uint_as_float((unsigned)(unsigned short)b[j] << 16);
    o[j] = (fa + fb) * inv;
  }
  ((f32x4*)out)[idx] = o;
}

// ---------- fallback (ws too small): single-pass 32q/wave ----------
__global__ __launch_bounds__(256, 2) void attn_single_kernel(
    const __hip_bfloat16* __restrict__ Q, const __hip_bfloat16* __restrict__ K,
    const __hip_bfloat16* __restrict__ Vt, float* __restrict__ out) {
  __shared__ __align__(16) short lds_k[2][64 * 64];
  __shared__ __align__(16) short lds_v[2][64 * 64];
  __shared__ float smc[4][32];
  const int bid = blockIdx.x;
  const int lin = (bid & 7) * 64 + (bid >> 3);
  const int h = lin >> 5, qb = lin & 31;
  const int t = threadIdx.x, lane = t & 63, w = t >> 6;
  const int lq = lane & 31, hi = lane >> 5;
  const short* Qh = (const short*)Q + ((size_t)h << 18);
  const short* Kh = (const short*)K + ((size_t)h << 18);
  const short* Vh = (const short*)Vt + ((size_t)h << 18);
  const int q0 = qb * 128 + w * 32;
  short8v qf[4];
#pragma unroll
  for (int kk = 0; kk < 4; ++kk)
    qf[kk] = *(const short8v*)&Qh[(q0 + lq) * 64 + kk * 16 + hi * 8];
  int off8[2][4];
#pragma unroll
  for (int half = 0; half < 2; ++half)
#pragma unroll
    for (int kk = 0; kk < 4; ++kk)
      off8[half][kk] = (half * 32 + lq) * 64 + (((kk * 2 + hi) ^ (lq & 7)) * 8);
  auto stage = [&](int kt, int b) {
#pragma unroll
    for (int i = 0; i < 2; ++i) {
      int c = w * 128 + i * 64 + lane;
      int row = c >> 3, ss = (c & 7) ^ (row & 7);
      gload_lds16(Kh + (size_t)(kt * 64 + row) * 64 + ss * 8, &lds_k[b][c * 8]);
    }
#pragma unroll
    for (int i = 0; i < 2; ++i) {
      int c = w * 128 + i * 64 + lane;
      int row = c >> 3, ss = (c & 7) ^ (row & 7);
      gload_lds16(Vh + (size_t)row * 4096 + kt * 64 + ss * 8, &lds_v[b][c * 8]);
    }
  };
  f32x16 o0 = {}, o1 = {};
  float l_r = 0.f;
  stage(0, 0);
  for (int kt = 0; kt < 64; ++kt) {
    const int cur = kt & 1;
    __builtin_amdgcn_s_barrier();
    if (kt + 1 < 64) {
      stage(kt + 1, cur ^ 1);
      asm volatile("s_waitcnt vmcnt(4)" ::: "memory");
    } else {
      asm volatile("s_waitcnt vmcnt(0)" ::: "memory");
    }
    __builtin_amdgcn_s_barrier();
    __builtin_amdgcn_sched_barrier(0);
    const short* kp = lds_k[cur];
    const short* vp = lds_v[cur];
    f32x16 s0 = {}, s1 = {};
#pragma unroll
    for (int kk = 0; kk < 4; ++kk) {
      short8v ka0 = *(const short8v*)&kp[off8[0][kk]];
      s0 = __builtin_amdgcn_mfma_f32_32x32x16_bf16(ka0, qf[kk], s0, 0, 0, 0);
      short8v ka1 = *(const short8v*)&kp[off8[1][kk]];
      s1 = __builtin_amdgcn_mfma_f32_32x32x16_bf16(ka1, qf[kk], s1, 0, 0, 0);
    }
#pragma unroll
    for (int j = 0; j < 16; ++j) { s0[j] = __builtin_amdgcn_exp2f(s0[j]); l_r += s0[j]; }
#pragma unroll
    for (int j = 0; j < 16; ++j) { s1[j] = __builtin_amdgcn_exp2f(s1[j]); l_r += s1[j]; }
    short8v pa[4];
#pragma unroll
    for (int half = 0; half < 2; ++half) {
      const f32x16& s = half ? s1 : s0;
#pragma unroll
      for (int g = 0; g < 2; ++g) {
        unsigned a0 = cvtpk(s[g * 8 + 0], s[g * 8 + 1]), a1 = cvtpk(s[g * 8 + 2], s[g * 8 + 3]);
        unsigned b0 = cvtpk(s[g * 8 + 4], s[g * 8 + 5]), b1 = cvtpk(s[g * 8 + 6], s[g * 8 + 7]);
        asm volatile("v_permlane32_swap_b32 %0, %1" : "+v"(a0), "+v"(b0));
        asm volatile("v_permlane32_swap_b32 %0, %1" : "+v"(a1), "+v"(b1));
        u32x4 u = {a0, a1, b0, b1};
        pa[half * 2 + g] = __builtin_bit_cast(short8v, u);
      }
    }
#pragma unroll
    for (int kk = 0; kk < 4; ++kk) {
      short8v vb0 = *(const short8v*)&vp[off8[0][kk]];
      o0 = __builtin_amdgcn_mfma_f32_32x32x16_bf16(pa[kk], vb0, o0, 0, 0, 0);
      short8v vb1 = *(const short8v*)&vp[off8[1][kk]];
      o1 = __builtin_amdgcn_mfma_f32_32x32x16_bf16(pa[kk], vb1, o1, 0, 0, 0);
    }
  }
  {
    float lt = l_r + __shfl_xor(l_r, 32);
    float inv = 1.0f / lt;
    if (lane < 32) smc[w][lq] = inv;
#pragma unroll
    for (int r = 0; r < 16; ++r) {
      int ql = (r & 3) + 8 * (r >> 2) + 4 * hi;
      float iv = smc[w][ql];
      int qg = q0 + ql;
      out[(size_t)qg * DMODEL + (h << 6) + lq] = o0[r] * iv;
      out[(size_t)qg * DMODEL + (h << 6) + 32 + lq] = o1[r] * iv;
    }
  }
}

extern "C" void kernel_launch(void* const* d_in, const int* in_sizes, int n_in,
                              void* d_out, int out_size, void* d_ws, size_t ws_size,
                              hipStream_t stream) {
  const float* node_emb = (const float*)d_in[0];
  const float* Wq = (const float*)d_in[1];
  const float* bq = (const float*)d_in[2];
  const float* Wk = (const float*)d_in[3];
  const float* bk = (const float*)d_in[4];
  const float* Wv = (const float*)d_in[5];
  const float* bv = (const float*)d_in[6];
  float* out = (float*)d_out;

  // ws layout: [Qb|Kb|Vtb live through attn][Xbf|WT dead after GEMM -> Opart/lpart overlay]
  const size_t HSZ = (size_t)NHEAD * N_NODES * HDIM;
  __hip_bfloat16* Qb  = (__hip_bfloat16*)d_ws;
  __hip_bfloat16* Kb  = Qb + HSZ;
  __hip_bfloat16* Vtb = Kb + HSZ;
  __hip_bfloat16* Xbf = Vtb + HSZ;
  __hip_bfloat16* WT  = Xbf + (size_t)N_NODES * DMODEL;

  __hip_bfloat16* Opart = Xbf;  // overlays Xbf/WT (dead after GEMM)
  float* lpart = (float*)(Opart + 2 * (size_t)N_NODES * DMODEL);

  const size_t split_bytes =
      (3 * HSZ + 2 * (size_t)N_NODES * DMODEL) * sizeof(__hip_bfloat16) +
      2 * (size_t)NHEAD * N_NODES * sizeof(float);
  const size_t base_bytes =
      (3 * HSZ + (size_t)N_NODES * DMODEL + (size_t)NOUT * DMODEL) * sizeof(__hip_bfloat16);
  const bool can_split = ws_size >= (split_bytes > base_bytes ? split_bytes : base_bytes);

  prep_kernel<<<4096 + 3072, 256, 0, stream>>>(node_emb, Xbf, Wq, Wk, Wv, WT);
  gemm_qkv_kernel<<<dim3(NOUT / 128, N_NODES / 128), 256, 0, stream>>>(
      Xbf, WT, bq, bk, bv, Qb, Kb, Vtb);

  if (can_split) {
    attn64_kernel<<<512, 256, 0, stream>>>(Qb, Kb, Vtb, Opart, lpart);
    combine_kernel<<<(N_NODES * DMODEL) / (256 * 4), 256, 0, stream>>>(Opart, lpart, out);
  } else {
    attn_single_kernel<<<512, 256, 0, stream>>>(Qb, Kb, Vtb, out);
  }
}